// Round 2
// baseline (2572.133 us; speedup 1.0000x reference)
//
#include <hip/hip_runtime.h>
#include <hip/hip_bf16.h>

// DGCF forward, MI355X. All f32 (reference dtype is float32 in & out).
#define NUSER 50000
#define NITEM 50000
#define NN    100000          // NUSER+NITEM
#define NNZ_  1000000
#define DIM_  64
#define FK_   4
#define DK_   16

static inline int ceil_div(int a, int b) { return (a + b - 1) / b; }

// ego = concat(user,item); acc = ego (first term of the 3-way mean).
__global__ void k_init(const float* __restrict__ eu,
                       const float* __restrict__ ei,
                       float* __restrict__ ego, float* __restrict__ acc) {
    int i = blockIdx.x * 256 + threadIdx.x;
    if (i >= NN * DIM_) return;
    float v = (i < NUSER * DIM_) ? eu[i] : ei[i - NUSER * DIM_];
    ego[i] = v;
    acc[i] = v;
}

__global__ void k_initA(float* __restrict__ A) {
    int i = blockIdx.x * 256 + threadIdx.x;
    if (i < FK_ * NNZ_) A[i] = 1.0f;
}

// Per edge: softmax over 4 factors of A -> vals; scatter-add vals into rowsum[head].
__global__ void k_rowsum(const float* __restrict__ A, const int* __restrict__ head,
                         float* __restrict__ vals, float* __restrict__ rowsum) {
    int e = blockIdx.x * 256 + threadIdx.x;
    if (e >= NNZ_) return;
    float a0 = A[e], a1 = A[NNZ_ + e], a2 = A[2 * NNZ_ + e], a3 = A[3 * NNZ_ + e];
    float m = fmaxf(fmaxf(a0, a1), fmaxf(a2, a3));
    float e0 = __expf(a0 - m), e1 = __expf(a1 - m), e2 = __expf(a2 - m), e3 = __expf(a3 - m);
    float inv = 1.0f / (e0 + e1 + e2 + e3);
    float v0 = e0 * inv, v1 = e1 * inv, v2 = e2 * inv, v3 = e3 * inv;
    vals[e] = v0; vals[NNZ_ + e] = v1; vals[2 * NNZ_ + e] = v2; vals[3 * NNZ_ + e] = v3;
    int h = head[e];
    atomicAdd(&rowsum[h], v0);
    atomicAdd(&rowsum[NN + h], v1);
    atomicAdd(&rowsum[2 * NN + h], v2);
    atomicAdd(&rowsum[3 * NN + h], v3);
}

// d = rowsum>0 ? 1/sqrt(max(rowsum,eps)) : 0   (in place)
__global__ void k_dinv(float* __restrict__ rs) {
    int i = blockIdx.x * 256 + threadIdx.x;
    if (i >= FK_ * NN) return;
    float v = rs[i];
    rs[i] = (v > 0.0f) ? 1.0f / sqrtf(fmaxf(v, 1e-12f)) : 0.0f;
}

// y[head][j] += vals[f][e] * d[f][tail] * ego[tail][j]   (64 lanes per edge, j = column)
__global__ void k_spmm(const float* __restrict__ vals, const float* __restrict__ d,
                       const float* __restrict__ ego,
                       const int* __restrict__ head, const int* __restrict__ tail,
                       float* __restrict__ y) {
    int g = blockIdx.x * 256 + threadIdx.x;
    int e = g >> 6;
    if (e >= NNZ_) return;
    int j = g & 63;
    int f = j >> 4;
    int h = head[e], t = tail[e];
    float v = vals[f * NNZ_ + e] * d[f * NN + t];
    float x = ego[t * 64 + j];
    atomicAdd(&y[h * 64 + j], v * x);
}

// factor_emb = d(head side) * y   (in place)
__global__ void k_scale(const float* __restrict__ d, float* __restrict__ y) {
    int i = blockIdx.x * 256 + threadIdx.x;
    if (i >= NN * DIM_) return;
    int n = i >> 6;
    int f = (i >> 4) & 3;
    y[i] *= d[f * NN + n];
}

// scores[f][e] = sum_d l2norm(fe[head]) * tanh(l2norm(ego[tail])); A += scores.
// 64 lanes/edge; 16-lane shuffle reductions (xor masks 1,2,4,8 stay inside the 16-group).
__global__ void k_scores(const float* __restrict__ fe, const float* __restrict__ ego,
                         const int* __restrict__ head, const int* __restrict__ tail,
                         float* __restrict__ A) {
    int g = blockIdx.x * 256 + threadIdx.x;
    int e = g >> 6;
    if (e >= NNZ_) return;
    int j = g & 63;
    int f = j >> 4;
    int dd = j & 15;
    int h = head[e], t = tail[e];

    float hx = fe[h * 64 + j];
    float sh = hx * hx;
    sh += __shfl_xor(sh, 1); sh += __shfl_xor(sh, 2);
    sh += __shfl_xor(sh, 4); sh += __shfl_xor(sh, 8);
    float hn = hx / fmaxf(sqrtf(sh), 1e-12f);

    float tx = ego[t * 64 + j];
    float st = tx * tx;
    st += __shfl_xor(st, 1); st += __shfl_xor(st, 2);
    st += __shfl_xor(st, 4); st += __shfl_xor(st, 8);
    float tn = tx / fmaxf(sqrtf(st), 1e-12f);
    // tanh(tn) via exp: tn in [-1,1] so no overflow concerns
    float ex = __expf(2.0f * tn);
    float th = (ex - 1.0f) / (ex + 1.0f);

    float p = hn * th;
    p += __shfl_xor(p, 1); p += __shfl_xor(p, 2);
    p += __shfl_xor(p, 4); p += __shfl_xor(p, 8);
    if (dd == 0) A[f * NNZ_ + e] += p;
}

// layer output: ego = l2norm(factor_emb per 16-chunk); acc += ego.
__global__ void k_layerout(const float* __restrict__ fe, float* __restrict__ ego,
                           float* __restrict__ acc) {
    int i = blockIdx.x * 256 + threadIdx.x;
    if (i >= NN * DIM_) return;
    float x = fe[i];
    float s = x * x;
    s += __shfl_xor(s, 1); s += __shfl_xor(s, 2);
    s += __shfl_xor(s, 4); s += __shfl_xor(s, 8);
    float v = x / fmaxf(sqrtf(s), 1e-12f);
    ego[i] = v;
    acc[i] += v;
}

__global__ void k_out(const float* __restrict__ acc, float* __restrict__ out, int n) {
    int i = blockIdx.x * 256 + threadIdx.x;
    if (i < n) out[i] = acc[i] * (1.0f / 3.0f);
}

extern "C" void kernel_launch(void* const* d_in, const int* in_sizes, int n_in,
                              void* d_out, int out_size, void* d_ws, size_t ws_size,
                              hipStream_t stream) {
    const float* eu = (const float*)d_in[0];
    const float* ei = (const float*)d_in[1];
    const int* head = (const int*)d_in[2];
    const int* tail = (const int*)d_in[3];

    // workspace layout (f32): ego | acc | y(factor_emb) | A | vals | rowsum/d
    float* ego  = (float*)d_ws;
    float* acc  = ego + (size_t)NN * DIM_;
    float* y    = acc + (size_t)NN * DIM_;
    float* A    = y   + (size_t)NN * DIM_;
    float* vals = A   + (size_t)FK_ * NNZ_;
    float* rs   = vals + (size_t)FK_ * NNZ_;
    // total: 3*6.4e6 + 2*4e6 + 0.4e6 floats = 27.6e6 floats = 110.4 MB

    const int node_blocks = ceil_div(NN * DIM_, 256);
    const int edge_blocks = ceil_div(NNZ_, 256);
    const int lane_blocks = ceil_div(NNZ_ * 64, 256);  // 64 lanes per edge

    k_init<<<node_blocks, 256, 0, stream>>>(eu, ei, ego, acc);
    k_initA<<<ceil_div(FK_ * NNZ_, 256), 256, 0, stream>>>(A);

    for (int layer = 0; layer < 2; ++layer) {
        for (int t = 0; t < 2; ++t) {
            hipMemsetAsync(rs, 0, (size_t)FK_ * NN * sizeof(float), stream);
            hipMemsetAsync(y, 0, (size_t)NN * DIM_ * sizeof(float), stream);
            k_rowsum<<<edge_blocks, 256, 0, stream>>>(A, head, vals, rs);
            k_dinv<<<ceil_div(FK_ * NN, 256), 256, 0, stream>>>(rs);
            k_spmm<<<lane_blocks, 256, 0, stream>>>(vals, rs, ego, head, tail, y);
            k_scale<<<node_blocks, 256, 0, stream>>>(rs, y);
            // Last scores update of the whole net is dead (A never read again) — skip it.
            if (!(layer == 1 && t == 1))
                k_scores<<<lane_blocks, 256, 0, stream>>>(y, ego, head, tail, A);
        }
        k_layerout<<<node_blocks, 256, 0, stream>>>(y, ego, acc);
    }
    k_out<<<ceil_div(out_size, 256), 256, 0, stream>>>(acc, (float*)d_out, out_size);
}

// Round 3
// 1398.529 us; speedup vs baseline: 1.8392x; 1.8392x over previous
//
#include <hip/hip_runtime.h>
#include <hip/hip_bf16.h>

// DGCF forward, MI355X. f32 in/out. CSR-based SpMM + per-node norm precompute.
#define NUSER 50000
#define NITEM 50000
#define NN    100000          // NUSER+NITEM
#define NNZ_  1000000
#define DIM_  64
#define FK_   4
#define DK_   16
#define SCAN_T 1024

static inline int ceil_div(int a, int b) { return (a + b - 1) / b; }

static __device__ inline float bf2f(unsigned short u) {
    unsigned int x = ((unsigned int)u) << 16;
    return __uint_as_float(x);
}
static __device__ inline unsigned short f2bf(float f) {
    // round-to-nearest-even bf16
    unsigned int x = __float_as_uint(f);
    unsigned int lsb = (x >> 16) & 1u;
    x += 0x7fffu + lsb;
    return (unsigned short)(x >> 16);
}

// ego0 = concat(user,item); out = ego0 (first term of the 3-way mean).
__global__ void k_init(const float* __restrict__ eu, const float* __restrict__ ei,
                       float* __restrict__ ego, float* __restrict__ out) {
    int i = blockIdx.x * 256 + threadIdx.x;
    if (i >= NN * DIM_) return;
    float v = (i < NUSER * DIM_) ? eu[i] : ei[i - NUSER * DIM_];
    ego[i] = v;
    out[i] = v;
}

__global__ void k_initA(float* __restrict__ A) {
    int i = blockIdx.x * 256 + threadIdx.x;
    if (i < FK_ * NNZ_) A[i] = 1.0f;
}

// ---- CSR build (graph is fixed; once per launch) ----
__global__ void k_hist(const int* __restrict__ head, int* __restrict__ deg) {
    int e = blockIdx.x * 256 + threadIdx.x;
    if (e < NNZ_) atomicAdd(&deg[head[e]], 1);
}

// exclusive scan of deg[0..NN) -> row_start[0..NN], single block of 1024.
__global__ void k_scan(const int* __restrict__ deg, int* __restrict__ row_start) {
    __shared__ int part[SCAN_T];
    int t = threadIdx.x;
    const int CH = (NN + SCAN_T - 1) / SCAN_T;   // 98
    int base = t * CH;
    int s = 0;
    for (int k = 0; k < CH; ++k) {
        int idx = base + k;
        if (idx < NN) s += deg[idx];
    }
    part[t] = s;
    __syncthreads();
    for (int off = 1; off < SCAN_T; off <<= 1) {
        int v = 0;
        if (t >= off) v = part[t - off];
        __syncthreads();
        if (t >= off) part[t] += v;
        __syncthreads();
    }
    int prefix = (t > 0) ? part[t - 1] : 0;      // exclusive prefix of this chunk
    for (int k = 0; k < CH; ++k) {
        int idx = base + k;
        if (idx < NN) { row_start[idx] = prefix; prefix += deg[idx]; }
    }
    if (t == SCAN_T - 1) row_start[NN] = prefix; // == NNZ_
}

// ---- per iteration ----
// softmax over 4 factors of A; scatter vals + tail into CSR slots (cursor-alloc).
__global__ void k_rowsum(const float* __restrict__ A, const int* __restrict__ head,
                         const int* __restrict__ tail,
                         const int* __restrict__ row_start, int* __restrict__ cursor,
                         float* __restrict__ vals_csr, int* __restrict__ csr_tail) {
    int e = blockIdx.x * 256 + threadIdx.x;
    if (e >= NNZ_) return;
    float a0 = A[e], a1 = A[NNZ_ + e], a2 = A[2 * NNZ_ + e], a3 = A[3 * NNZ_ + e];
    float m = fmaxf(fmaxf(a0, a1), fmaxf(a2, a3));
    float e0 = __expf(a0 - m), e1 = __expf(a1 - m), e2 = __expf(a2 - m), e3 = __expf(a3 - m);
    float inv = 1.0f / (e0 + e1 + e2 + e3);
    int h = head[e];
    int pos = row_start[h] + atomicAdd(&cursor[h], 1);
    vals_csr[pos]            = e0 * inv;
    vals_csr[NNZ_ + pos]     = e1 * inv;
    vals_csr[2 * NNZ_ + pos] = e2 * inv;
    vals_csr[3 * NNZ_ + pos] = e3 * inv;
    csr_tail[pos] = tail[e];
}

// d[f][n] = g(segment-sum of vals_csr over row n); no atomics.
__global__ void k_dinv(const float* __restrict__ vals_csr, const int* __restrict__ row_start,
                       float* __restrict__ d) {
    int n = blockIdx.x * 256 + threadIdx.x;
    if (n >= NN) return;
    int f = blockIdx.y;
    int r0 = row_start[n], r1 = row_start[n + 1];
    float s = 0.0f;
    const float* v = vals_csr + (size_t)f * NNZ_;
    for (int k = r0; k < r1; ++k) s += v[k];
    d[f * NN + n] = (s > 0.0f) ? 1.0f / sqrtf(fmaxf(s, 1e-12f)) : 0.0f;
}

// One wave per node: factor_emb = d_head * sum_e vals*d_tail*ego[tail]; then
// fused chunk-l2norm -> fn (fn IS normalize(factor_emb) = scores input = layer output).
__global__ void k_spmm(const float* __restrict__ vals_csr, const float* __restrict__ d,
                       const float* __restrict__ ego,
                       const int* __restrict__ row_start, const int* __restrict__ csr_tail,
                       float* __restrict__ fn) {
    int n = (blockIdx.x * 256 + threadIdx.x) >> 6;
    if (n >= NN) return;
    int j = threadIdx.x & 63;
    int f = j >> 4;
    int r0 = row_start[n], r1 = row_start[n + 1];
    const float* v = vals_csr + (size_t)f * NNZ_;
    const float* df = d + (size_t)f * NN;
    float acc = 0.0f;
    for (int k = r0; k < r1; ++k) {
        int t = csr_tail[k];
        acc += v[k] * df[t] * ego[t * 64 + j];
    }
    float val = acc * df[n];
    float s = val * val;
    s += __shfl_xor(s, 1); s += __shfl_xor(s, 2);
    s += __shfl_xor(s, 4); s += __shfl_xor(s, 8);
    fn[n * 64 + j] = val / fmaxf(sqrtf(s), 1e-12f);
}

// te = tanh(l2norm per 16-chunk of ego), bf16. Once per layer.
__global__ void k_prep_te(const float* __restrict__ ego, unsigned short* __restrict__ te) {
    int i = blockIdx.x * 256 + threadIdx.x;
    if (i >= NN * DIM_) return;
    float x = ego[i];
    float s = x * x;
    s += __shfl_xor(s, 1); s += __shfl_xor(s, 2);
    s += __shfl_xor(s, 4); s += __shfl_xor(s, 8);
    float nrm = x / fmaxf(sqrtf(s), 1e-12f);
    float ex = __expf(2.0f * nrm);          // nrm in [-1,1], no overflow
    te[i] = f2bf((ex - 1.0f) / (ex + 1.0f));
}

// 16 lanes/edge: A[f][e] += dot(fn[head] chunk, te[tail] chunk). No atomics.
__global__ void k_scores(const float* __restrict__ fn, const unsigned short* __restrict__ te,
                         const int* __restrict__ head, const int* __restrict__ tail,
                         float* __restrict__ A) {
    int g = blockIdx.x * 256 + threadIdx.x;
    int e = g >> 4;
    if (e >= NNZ_) return;
    int l = g & 15;                // 4 elements per lane
    int f = l >> 2;
    int h = head[e], t = tail[e];
    float4 hv = *(const float4*)&fn[h * 64 + l * 4];
    ushort4 tu = *(const ushort4*)&te[t * 64 + l * 4];
    float p = hv.x * bf2f(tu.x) + hv.y * bf2f(tu.y) + hv.z * bf2f(tu.z) + hv.w * bf2f(tu.w);
    p += __shfl_xor(p, 1); p += __shfl_xor(p, 2);
    if ((l & 3) == 0) A[f * NNZ_ + e] += p;
}

__global__ void k_acc(const float* __restrict__ fn, float* __restrict__ out) {
    int i = blockIdx.x * 256 + threadIdx.x;
    if (i < NN * DIM_) out[i] += fn[i];
}

__global__ void k_out(float* __restrict__ out, int nelem) {
    int i = blockIdx.x * 256 + threadIdx.x;
    if (i < nelem) out[i] *= (1.0f / 3.0f);
}

extern "C" void kernel_launch(void* const* d_in, const int* in_sizes, int n_in,
                              void* d_out, int out_size, void* d_ws, size_t ws_size,
                              hipStream_t stream) {
    const float* eu = (const float*)d_in[0];
    const float* ei = (const float*)d_in[1];
    const int* head = (const int*)d_in[2];
    const int* tail = (const int*)d_in[3];
    float* out = (float*)d_out;   // doubles as the 3-term accumulator

    // workspace layout — 102.8 MB total (<110.4 MB proven available)
    float* ego0 = (float*)d_ws;                       // 6.4M f32
    float* ego1 = ego0 + (size_t)NN * DIM_;           // 6.4M f32
    unsigned short* te = (unsigned short*)(ego1 + (size_t)NN * DIM_);  // 6.4M bf16
    float* A    = (float*)(te + (size_t)NN * DIM_);   // 4M f32
    float* vals = A + (size_t)FK_ * NNZ_;             // 4M f32 (CSR order)
    float* d    = vals + (size_t)FK_ * NNZ_;          // 0.4M f32
    int* row_start = (int*)(d + (size_t)FK_ * NN);    // NN+1
    int* deg    = row_start + (NN + 1);               // NN
    int* cursor = deg + NN;                           // NN
    int* csr_tail = cursor + NN;                      // 1M

    const int node_blocks = ceil_div(NN * DIM_, 256);       // 25000
    const int edge_blocks = ceil_div(NNZ_, 256);            // 3907
    const int score_blocks = ceil_div(NNZ_ * 16, 256);      // 62500
    const int spmm_blocks = ceil_div(NN * 64, 256);         // 25000

    k_init<<<node_blocks, 256, 0, stream>>>(eu, ei, ego0, out);
    k_initA<<<ceil_div(FK_ * NNZ_, 256), 256, 0, stream>>>(A);

    // CSR build (graph constant within a launch)
    hipMemsetAsync(deg, 0, NN * sizeof(int), stream);
    k_hist<<<edge_blocks, 256, 0, stream>>>(head, deg);
    k_scan<<<1, SCAN_T, 0, stream>>>(deg, row_start);

    float* ego = ego0;
    float* fn  = ego1;
    for (int layer = 0; layer < 2; ++layer) {
        k_prep_te<<<node_blocks, 256, 0, stream>>>(ego, te);
        for (int t = 0; t < 2; ++t) {
            hipMemsetAsync(cursor, 0, NN * sizeof(int), stream);
            k_rowsum<<<edge_blocks, 256, 0, stream>>>(A, head, tail, row_start, cursor,
                                                      vals, csr_tail);
            dim3 dgrid(ceil_div(NN, 256), FK_);
            k_dinv<<<dgrid, 256, 0, stream>>>(vals, row_start, d);
            k_spmm<<<spmm_blocks, 256, 0, stream>>>(vals, d, ego, row_start, csr_tail, fn);
            // Last scores update of the whole net is dead (A never read again) — skip.
            if (!(layer == 1 && t == 1))
                k_scores<<<score_blocks, 256, 0, stream>>>(fn, te, head, tail, A);
        }
        k_acc<<<node_blocks, 256, 0, stream>>>(fn, out);
        float* tmp = ego; ego = fn; fn = tmp;   // fn becomes next layer's ego
    }
    k_out<<<node_blocks, 256, 0, stream>>>(out, NN * DIM_);
}

// Round 4
// 1226.881 us; speedup vs baseline: 2.0965x; 1.1399x over previous
//
#include <hip/hip_runtime.h>
#include <hip/hip_bf16.h>

// DGCF forward, MI355X. f32 in/out. CSR SpMM + per-node norm precompute.
// R4: replaced single-block k_scan (192us, one CU) with 3-kernel decoupled scan.
#define NUSER 50000
#define NITEM 50000
#define NN    100000          // NUSER+NITEM
#define NNZ_  1000000
#define DIM_  64
#define FK_   4
#define DK_   16

static inline int ceil_div(int a, int b) { return (a + b - 1) / b; }
#define NBLK 391              // ceil_div(NN,256)

static __device__ inline float bf2f(unsigned short u) {
    unsigned int x = ((unsigned int)u) << 16;
    return __uint_as_float(x);
}
static __device__ inline unsigned short f2bf(float f) {
    unsigned int x = __float_as_uint(f);
    unsigned int lsb = (x >> 16) & 1u;
    x += 0x7fffu + lsb;
    return (unsigned short)(x >> 16);
}

// ego0 = concat(user,item); out = ego0 (first term of the 3-way mean).
__global__ void k_init(const float* __restrict__ eu, const float* __restrict__ ei,
                       float* __restrict__ ego, float* __restrict__ out) {
    int i = blockIdx.x * 256 + threadIdx.x;
    if (i >= NN * DIM_) return;
    float v = (i < NUSER * DIM_) ? eu[i] : ei[i - NUSER * DIM_];
    ego[i] = v;
    out[i] = v;
}

__global__ void k_initA(float* __restrict__ A) {
    int i = blockIdx.x * 256 + threadIdx.x;
    if (i < FK_ * NNZ_) A[i] = 1.0f;
}

// ---- CSR build (graph fixed; once per launch) ----
__global__ void k_hist(const int* __restrict__ head, int* __restrict__ deg) {
    int e = blockIdx.x * 256 + threadIdx.x;
    if (e < NNZ_) atomicAdd(&deg[head[e]], 1);
}

// per-block sum of 256 degrees
__global__ void k_blksum(const int* __restrict__ deg, int* __restrict__ partials) {
    __shared__ int sh[256];
    int i = blockIdx.x * 256 + threadIdx.x;
    int v = (i < NN) ? deg[i] : 0;
    sh[threadIdx.x] = v;
    __syncthreads();
    for (int off = 128; off > 0; off >>= 1) {
        if (threadIdx.x < off) sh[threadIdx.x] += sh[threadIdx.x + off];
        __syncthreads();
    }
    if (threadIdx.x == 0) partials[blockIdx.x] = sh[0];
}

// exclusive scan of NBLK partials (single block of 512); writes row_start[NN]=total.
__global__ void k_scanp(const int* __restrict__ partials, int* __restrict__ blk_off,
                        int* __restrict__ row_start_end) {
    __shared__ int sh[512];
    int t = threadIdx.x;
    int v = (t < NBLK) ? partials[t] : 0;
    sh[t] = v;
    __syncthreads();
    for (int off = 1; off < 512; off <<= 1) {
        int u = 0;
        if (t >= off) u = sh[t - off];
        __syncthreads();
        sh[t] += u;
        __syncthreads();
    }
    if (t < NBLK) blk_off[t] = sh[t] - v;       // exclusive
    if (t == 511) row_start_end[0] = sh[511];   // == NNZ_
}

// in-block exclusive scan + block offset -> row_start (coalesced)
__global__ void k_fill(const int* __restrict__ deg, const int* __restrict__ blk_off,
                       int* __restrict__ row_start) {
    __shared__ int sh[256];
    int i = blockIdx.x * 256 + threadIdx.x;
    int v = (i < NN) ? deg[i] : 0;
    sh[threadIdx.x] = v;
    __syncthreads();
    for (int off = 1; off < 256; off <<= 1) {
        int u = 0;
        if (threadIdx.x >= off) u = sh[threadIdx.x - off];
        __syncthreads();
        sh[threadIdx.x] += u;
        __syncthreads();
    }
    if (i < NN) row_start[i] = blk_off[blockIdx.x] + sh[threadIdx.x] - v;
}

// ---- per iteration ----
// softmax over 4 factors of A; scatter vals + tail into CSR slots (cursor-alloc).
__global__ void k_rowsum(const float* __restrict__ A, const int* __restrict__ head,
                         const int* __restrict__ tail,
                         const int* __restrict__ row_start, int* __restrict__ cursor,
                         float* __restrict__ vals_csr, int* __restrict__ csr_tail) {
    int e = blockIdx.x * 256 + threadIdx.x;
    if (e >= NNZ_) return;
    float a0 = A[e], a1 = A[NNZ_ + e], a2 = A[2 * NNZ_ + e], a3 = A[3 * NNZ_ + e];
    float m = fmaxf(fmaxf(a0, a1), fmaxf(a2, a3));
    float e0 = __expf(a0 - m), e1 = __expf(a1 - m), e2 = __expf(a2 - m), e3 = __expf(a3 - m);
    float inv = 1.0f / (e0 + e1 + e2 + e3);
    int h = head[e];
    int pos = row_start[h] + atomicAdd(&cursor[h], 1);
    vals_csr[pos]            = e0 * inv;
    vals_csr[NNZ_ + pos]     = e1 * inv;
    vals_csr[2 * NNZ_ + pos] = e2 * inv;
    vals_csr[3 * NNZ_ + pos] = e3 * inv;
    csr_tail[pos] = tail[e];
}

// d[f][n] = g(segment-sum of vals_csr over row n); no atomics.
__global__ void k_dinv(const float* __restrict__ vals_csr, const int* __restrict__ row_start,
                       float* __restrict__ d) {
    int n = blockIdx.x * 256 + threadIdx.x;
    if (n >= NN) return;
    int f = blockIdx.y;
    int r0 = row_start[n], r1 = row_start[n + 1];
    float s = 0.0f;
    const float* v = vals_csr + (size_t)f * NNZ_;
    for (int k = r0; k < r1; ++k) s += v[k];
    d[f * NN + n] = (s > 0.0f) ? 1.0f / sqrtf(fmaxf(s, 1e-12f)) : 0.0f;
}

// One wave per node: factor_emb = d_head * sum_e vals*d_tail*ego[tail]; then
// fused chunk-l2norm -> fn (fn IS normalize(factor_emb) = scores input = layer output).
__global__ void k_spmm(const float* __restrict__ vals_csr, const float* __restrict__ d,
                       const float* __restrict__ ego,
                       const int* __restrict__ row_start, const int* __restrict__ csr_tail,
                       float* __restrict__ fn) {
    int n = (blockIdx.x * 256 + threadIdx.x) >> 6;
    if (n >= NN) return;
    int j = threadIdx.x & 63;
    int f = j >> 4;
    int r0 = row_start[n], r1 = row_start[n + 1];
    const float* v = vals_csr + (size_t)f * NNZ_;
    const float* df = d + (size_t)f * NN;
    float acc = 0.0f;
    for (int k = r0; k < r1; ++k) {
        int t = csr_tail[k];
        acc += v[k] * df[t] * ego[t * 64 + j];
    }
    float val = acc * df[n];
    float s = val * val;
    s += __shfl_xor(s, 1); s += __shfl_xor(s, 2);
    s += __shfl_xor(s, 4); s += __shfl_xor(s, 8);
    fn[n * 64 + j] = val / fmaxf(sqrtf(s), 1e-12f);
}

// te = tanh(l2norm per 16-chunk of ego), bf16. Once per layer.
__global__ void k_prep_te(const float* __restrict__ ego, unsigned short* __restrict__ te) {
    int i = blockIdx.x * 256 + threadIdx.x;
    if (i >= NN * DIM_) return;
    float x = ego[i];
    float s = x * x;
    s += __shfl_xor(s, 1); s += __shfl_xor(s, 2);
    s += __shfl_xor(s, 4); s += __shfl_xor(s, 8);
    float nrm = x / fmaxf(sqrtf(s), 1e-12f);
    float ex = __expf(2.0f * nrm);          // nrm in [-1,1], no overflow
    te[i] = f2bf((ex - 1.0f) / (ex + 1.0f));
}

// 16 lanes/edge: A[f][e] += dot(fn[head] chunk, te[tail] chunk). No atomics.
__global__ void k_scores(const float* __restrict__ fn, const unsigned short* __restrict__ te,
                         const int* __restrict__ head, const int* __restrict__ tail,
                         float* __restrict__ A) {
    int g = blockIdx.x * 256 + threadIdx.x;
    int e = g >> 4;
    if (e >= NNZ_) return;
    int l = g & 15;                // 4 elements per lane
    int f = l >> 2;
    int h = head[e], t = tail[e];
    float4 hv = *(const float4*)&fn[h * 64 + l * 4];
    ushort4 tu = *(const ushort4*)&te[t * 64 + l * 4];
    float p = hv.x * bf2f(tu.x) + hv.y * bf2f(tu.y) + hv.z * bf2f(tu.z) + hv.w * bf2f(tu.w);
    p += __shfl_xor(p, 1); p += __shfl_xor(p, 2);
    if ((l & 3) == 0) A[f * NNZ_ + e] += p;
}

__global__ void k_acc(const float* __restrict__ fn, float* __restrict__ out) {
    int i = blockIdx.x * 256 + threadIdx.x;
    if (i < NN * DIM_) out[i] += fn[i];
}

__global__ void k_out(float* __restrict__ out, int nelem) {
    int i = blockIdx.x * 256 + threadIdx.x;
    if (i < nelem) out[i] *= (1.0f / 3.0f);
}

extern "C" void kernel_launch(void* const* d_in, const int* in_sizes, int n_in,
                              void* d_out, int out_size, void* d_ws, size_t ws_size,
                              hipStream_t stream) {
    const float* eu = (const float*)d_in[0];
    const float* ei = (const float*)d_in[1];
    const int* head = (const int*)d_in[2];
    const int* tail = (const int*)d_in[3];
    float* out = (float*)d_out;   // doubles as the 3-term accumulator

    // workspace layout — ~102.8 MB total (<110.4 MB proven available)
    float* ego0 = (float*)d_ws;                       // 6.4M f32
    float* ego1 = ego0 + (size_t)NN * DIM_;           // 6.4M f32
    unsigned short* te = (unsigned short*)(ego1 + (size_t)NN * DIM_);  // 6.4M bf16
    float* A    = (float*)(te + (size_t)NN * DIM_);   // 4M f32
    float* vals = A + (size_t)FK_ * NNZ_;             // 4M f32 (CSR order)
    float* d    = vals + (size_t)FK_ * NNZ_;          // 0.4M f32
    int* row_start = (int*)(d + (size_t)FK_ * NN);    // NN+1
    int* deg    = row_start + (NN + 1);               // NN
    int* cursor = deg + NN;                           // NN
    int* csr_tail = cursor + NN;                      // 1M
    int* partials = csr_tail + NNZ_;                  // NBLK
    int* blk_off  = partials + NBLK;                  // NBLK

    const int node_blocks = ceil_div(NN * DIM_, 256);       // 25000
    const int edge_blocks = ceil_div(NNZ_, 256);            // 3907
    const int score_blocks = ceil_div(NNZ_ * 16, 256);      // 62500
    const int spmm_blocks = ceil_div(NN * 64, 256);         // 25000

    k_init<<<node_blocks, 256, 0, stream>>>(eu, ei, ego0, out);
    k_initA<<<ceil_div(FK_ * NNZ_, 256), 256, 0, stream>>>(A);

    // CSR build (graph constant within a launch) — decoupled 3-phase scan
    hipMemsetAsync(deg, 0, NN * sizeof(int), stream);
    k_hist<<<edge_blocks, 256, 0, stream>>>(head, deg);
    k_blksum<<<NBLK, 256, 0, stream>>>(deg, partials);
    k_scanp<<<1, 512, 0, stream>>>(partials, blk_off, &row_start[NN]);
    k_fill<<<NBLK, 256, 0, stream>>>(deg, blk_off, row_start);

    float* ego = ego0;
    float* fn  = ego1;
    for (int layer = 0; layer < 2; ++layer) {
        k_prep_te<<<node_blocks, 256, 0, stream>>>(ego, te);
        for (int t = 0; t < 2; ++t) {
            hipMemsetAsync(cursor, 0, NN * sizeof(int), stream);
            k_rowsum<<<edge_blocks, 256, 0, stream>>>(A, head, tail, row_start, cursor,
                                                      vals, csr_tail);
            dim3 dgrid(ceil_div(NN, 256), FK_);
            k_dinv<<<dgrid, 256, 0, stream>>>(vals, row_start, d);
            k_spmm<<<spmm_blocks, 256, 0, stream>>>(vals, d, ego, row_start, csr_tail, fn);
            // Last scores update of the whole net is dead (A never read again) — skip.
            if (!(layer == 1 && t == 1))
                k_scores<<<score_blocks, 256, 0, stream>>>(fn, te, head, tail, A);
        }
        k_acc<<<node_blocks, 256, 0, stream>>>(fn, out);
        float* tmp = ego; ego = fn; fn = tmp;   // fn becomes next layer's ego
    }
    k_out<<<node_blocks, 256, 0, stream>>>(out, NN * DIM_);
}

// Round 5
// 863.350 us; speedup vs baseline: 2.9792x; 1.4211x over previous
//
#include <hip/hip_runtime.h>
#include <hip/hip_bf16.h>

// DGCF forward, MI355X. f32 in/out.
// R5: A lives in CSR order as float4[NNZ] (no per-iter scatter, no vals array);
// scores fused into spmm (fn stays in registers); fused layer-end epilogue;
// unroll-by-2 gather loops for MLP.
#define NUSER 50000
#define NITEM 50000
#define NN    100000          // NUSER+NITEM
#define NNZ_  1000000
#define DIM_  64
#define FK_   4
#define NBLK  391             // ceil_div(NN,256)

#define FL_SCORES 1
#define FL_OUT    2
#define FL_NEXT   4

static inline int ceil_div(int a, int b) { return (a + b - 1) / b; }

static __device__ inline float bf2f(unsigned short u) {
    return __uint_as_float(((unsigned int)u) << 16);
}
static __device__ inline unsigned short f2bf(float f) {
    unsigned int x = __float_as_uint(f);
    x += 0x7fffu + ((x >> 16) & 1u);
    return (unsigned short)(x >> 16);
}
// softmax weight of factor f from the 4 A-values of one edge (f wave-uniform per 16-group)
static __device__ inline float smx(float4 a, int f) {
    float m = fmaxf(fmaxf(a.x, a.y), fmaxf(a.z, a.w));
    float e0 = __expf(a.x - m), e1 = __expf(a.y - m), e2 = __expf(a.z - m), e3 = __expf(a.w - m);
    float ef = (f == 0) ? e0 : (f == 1) ? e1 : (f == 2) ? e2 : e3;
    return ef / (e0 + e1 + e2 + e3);
}

// ego = concat(user,item); out = ego (first term of the 3-way mean).
__global__ void k_init(const float* __restrict__ eu, const float* __restrict__ ei,
                       float* __restrict__ ego, float* __restrict__ out) {
    int i = blockIdx.x * 256 + threadIdx.x;
    if (i >= NN * DIM_) return;
    float v = (i < NUSER * DIM_) ? eu[i] : ei[i - NUSER * DIM_];
    ego[i] = v;
    out[i] = v;
}

__global__ void k_initA(float4* __restrict__ A4) {
    int e = blockIdx.x * 256 + threadIdx.x;
    if (e < NNZ_) A4[e] = make_float4(1.0f, 1.0f, 1.0f, 1.0f);
}

// ---- CSR build (once per launch) ----
__global__ void k_hist(const int* __restrict__ head, int* __restrict__ deg) {
    int e = blockIdx.x * 256 + threadIdx.x;
    if (e < NNZ_) atomicAdd(&deg[head[e]], 1);
}

__global__ void k_blksum(const int* __restrict__ deg, int* __restrict__ partials) {
    __shared__ int sh[256];
    int i = blockIdx.x * 256 + threadIdx.x;
    sh[threadIdx.x] = (i < NN) ? deg[i] : 0;
    __syncthreads();
    for (int off = 128; off > 0; off >>= 1) {
        if (threadIdx.x < off) sh[threadIdx.x] += sh[threadIdx.x + off];
        __syncthreads();
    }
    if (threadIdx.x == 0) partials[blockIdx.x] = sh[0];
}

__global__ void k_scanp(const int* __restrict__ partials, int* __restrict__ blk_off,
                        int* __restrict__ row_start_end) {
    __shared__ int sh[512];
    int t = threadIdx.x;
    int v = (t < NBLK) ? partials[t] : 0;
    sh[t] = v;
    __syncthreads();
    for (int off = 1; off < 512; off <<= 1) {
        int u = 0;
        if (t >= off) u = sh[t - off];
        __syncthreads();
        sh[t] += u;
        __syncthreads();
    }
    if (t < NBLK) blk_off[t] = sh[t] - v;
    if (t == 511) row_start_end[0] = sh[511];
}

__global__ void k_fill(const int* __restrict__ deg, const int* __restrict__ blk_off,
                       int* __restrict__ row_start) {
    __shared__ int sh[256];
    int i = blockIdx.x * 256 + threadIdx.x;
    int v = (i < NN) ? deg[i] : 0;
    sh[threadIdx.x] = v;
    __syncthreads();
    for (int off = 1; off < 256; off <<= 1) {
        int u = 0;
        if (threadIdx.x >= off) u = sh[threadIdx.x - off];
        __syncthreads();
        sh[threadIdx.x] += u;
        __syncthreads();
    }
    if (i < NN) row_start[i] = blk_off[blockIdx.x] + sh[threadIdx.x] - v;
}

__global__ void k_csrfill(const int* __restrict__ head, const int* __restrict__ tail,
                          const int* __restrict__ row_start, int* __restrict__ cursor,
                          int* __restrict__ csr_tail) {
    int e = blockIdx.x * 256 + threadIdx.x;
    if (e >= NNZ_) return;
    int h = head[e];
    int pos = row_start[h] + atomicAdd(&cursor[h], 1);
    csr_tail[pos] = tail[e];
}

// ---- per iteration ----
// d4[n] = g(rowsum of softmax(A4) per factor); thread per node, streaming A4.
__global__ void k_dinv(const float4* __restrict__ A4, const int* __restrict__ row_start,
                       float4* __restrict__ d4) {
    int n = blockIdx.x * 256 + threadIdx.x;
    if (n >= NN) return;
    int r0 = row_start[n], r1 = row_start[n + 1];
    float s0 = 0.f, s1 = 0.f, s2 = 0.f, s3 = 0.f;
    for (int k = r0; k < r1; ++k) {
        float4 a = A4[k];
        float m = fmaxf(fmaxf(a.x, a.y), fmaxf(a.z, a.w));
        float e0 = __expf(a.x - m), e1 = __expf(a.y - m), e2 = __expf(a.z - m), e3 = __expf(a.w - m);
        float inv = 1.0f / (e0 + e1 + e2 + e3);
        s0 += e0 * inv; s1 += e1 * inv; s2 += e2 * inv; s3 += e3 * inv;
    }
    float4 d;
    d.x = (s0 > 0.f) ? 1.0f / sqrtf(fmaxf(s0, 1e-12f)) : 0.f;
    d.y = (s1 > 0.f) ? 1.0f / sqrtf(fmaxf(s1, 1e-12f)) : 0.f;
    d.z = (s2 > 0.f) ? 1.0f / sqrtf(fmaxf(s2, 1e-12f)) : 0.f;
    d.w = (s3 > 0.f) ? 1.0f / sqrtf(fmaxf(s3, 1e-12f)) : 0.f;
    d4[n] = d;
}

// te = tanh(l2norm per 16-chunk of ego), bf16. Layer 0 only (later layers fused).
__global__ void k_prep_te(const float* __restrict__ ego, unsigned short* __restrict__ te) {
    int i = blockIdx.x * 256 + threadIdx.x;
    if (i >= NN * DIM_) return;
    float x = ego[i];
    float s = x * x;
    s += __shfl_xor(s, 1); s += __shfl_xor(s, 2);
    s += __shfl_xor(s, 4); s += __shfl_xor(s, 8);
    float nrm = x / fmaxf(sqrtf(s), 1e-12f);
    float ex = __expf(2.0f * nrm);
    te[i] = f2bf((ex - 1.0f) / (ex + 1.0f));
}

// One wave per node. Compute loop: factor_emb via CSR gather + in-reg softmax.
// fn = chunk-l2norm (registers only). Optional scores pass (A4 += dot(fn, te[tail])),
// optional out-accumulate, optional next-layer ego/te writes (fn already unit-norm).
__global__ void k_fused(const float4* __restrict__ A4v, const float4* __restrict__ d4,
                        const float* __restrict__ ego,
                        const int* __restrict__ row_start, const int* __restrict__ csr_tail,
                        const unsigned short* __restrict__ te,
                        float4* __restrict__ A4w,
                        float* __restrict__ out, float* __restrict__ ego_next,
                        unsigned short* __restrict__ te_next, int flags) {
    int n = (blockIdx.x * 256 + threadIdx.x) >> 6;
    if (n >= NN) return;
    int j = threadIdx.x & 63;
    int f = j >> 4;
    int r0 = row_start[n], r1 = row_start[n + 1];

    float acc = 0.0f;
    int k = r0;
    for (; k + 1 < r1; k += 2) {
        int t0 = csr_tail[k], t1 = csr_tail[k + 1];
        float4 a0 = A4v[k], a1 = A4v[k + 1];
        float x0 = ego[t0 * 64 + j], x1 = ego[t1 * 64 + j];
        float dt0 = ((const float*)(d4 + t0))[f];
        float dt1 = ((const float*)(d4 + t1))[f];
        acc += smx(a0, f) * dt0 * x0;
        acc += smx(a1, f) * dt1 * x1;
    }
    if (k < r1) {
        int t0 = csr_tail[k];
        float4 a0 = A4v[k];
        acc += smx(a0, f) * ((const float*)(d4 + t0))[f] * ego[t0 * 64 + j];
    }

    float val = acc * ((const float*)(d4 + n))[f];
    float s = val * val;
    s += __shfl_xor(s, 1); s += __shfl_xor(s, 2);
    s += __shfl_xor(s, 4); s += __shfl_xor(s, 8);
    float fn = val / fmaxf(sqrtf(s), 1e-12f);

    if (flags & FL_SCORES) {
        int k2 = r0;
        for (; k2 + 1 < r1; k2 += 2) {
            int t0 = csr_tail[k2], t1 = csr_tail[k2 + 1];
            float p0 = fn * bf2f(te[t0 * 64 + j]);
            float p1 = fn * bf2f(te[t1 * 64 + j]);
            p0 += __shfl_xor(p0, 1); p1 += __shfl_xor(p1, 1);
            p0 += __shfl_xor(p0, 2); p1 += __shfl_xor(p1, 2);
            p0 += __shfl_xor(p0, 4); p1 += __shfl_xor(p1, 4);
            p0 += __shfl_xor(p0, 8); p1 += __shfl_xor(p1, 8);
            if ((j & 15) == 0) {
                ((float*)(A4w + k2))[f] += p0;
                ((float*)(A4w + k2 + 1))[f] += p1;
            }
        }
        if (k2 < r1) {
            int t0 = csr_tail[k2];
            float p0 = fn * bf2f(te[t0 * 64 + j]);
            p0 += __shfl_xor(p0, 1); p0 += __shfl_xor(p0, 2);
            p0 += __shfl_xor(p0, 4); p0 += __shfl_xor(p0, 8);
            if ((j & 15) == 0) ((float*)(A4w + k2))[f] += p0;
        }
    }
    if (flags & FL_OUT) out[n * 64 + j] += fn;
    if (flags & FL_NEXT) {
        ego_next[n * 64 + j] = fn;
        float ex = __expf(2.0f * fn);
        te_next[n * 64 + j] = f2bf((ex - 1.0f) / (ex + 1.0f));
    }
}

__global__ void k_out(float* __restrict__ out, int nelem) {
    int i = blockIdx.x * 256 + threadIdx.x;
    if (i < nelem) out[i] *= (1.0f / 3.0f);
}

extern "C" void kernel_launch(void* const* d_in, const int* in_sizes, int n_in,
                              void* d_out, int out_size, void* d_ws, size_t ws_size,
                              hipStream_t stream) {
    const float* eu = (const float*)d_in[0];
    const float* ei = (const float*)d_in[1];
    const int* head = (const int*)d_in[2];
    const int* tail = (const int*)d_in[3];
    float* out = (float*)d_out;   // 3-term accumulator, scaled at the end

    // workspace layout — ~98.8 MB
    float* ego_a = (float*)d_ws;                           // 6.4M f32  (25.6 MB)
    float* ego_b = ego_a + (size_t)NN * DIM_;              // 6.4M f32  (25.6 MB)
    unsigned short* te_a = (unsigned short*)(ego_b + (size_t)NN * DIM_); // 12.8 MB
    unsigned short* te_b = te_a + (size_t)NN * DIM_;       // 12.8 MB
    float4* A4 = (float4*)(te_b + (size_t)NN * DIM_);      // NNZ f4    (16 MB)
    float4* d4 = A4 + (size_t)NNZ_;                        // NN f4     (1.6 MB)
    int* row_start = (int*)(d4 + NN);                      // NN+1
    int* deg    = row_start + (NN + 1);                    // NN
    int* cursor = deg + NN;                                // NN
    int* csr_tail = cursor + NN;                           // 1M (4 MB)
    int* partials = csr_tail + NNZ_;                       // NBLK
    int* blk_off  = partials + NBLK;                       // NBLK

    const int node_blocks = ceil_div(NN * DIM_, 256);      // 25000
    const int edge_blocks = ceil_div(NNZ_, 256);           // 3907
    const int wave_blocks = ceil_div(NN * 64, 256);        // 25000
    const int dinv_blocks = ceil_div(NN, 256);             // 391

    k_init<<<node_blocks, 256, 0, stream>>>(eu, ei, ego_a, out);
    k_initA<<<edge_blocks, 256, 0, stream>>>(A4);

    // CSR build (graph constant within a launch)
    hipMemsetAsync(deg, 0, NN * sizeof(int), stream);
    k_hist<<<edge_blocks, 256, 0, stream>>>(head, deg);
    k_blksum<<<NBLK, 256, 0, stream>>>(deg, partials);
    k_scanp<<<1, 512, 0, stream>>>(partials, blk_off, &row_start[NN]);
    k_fill<<<NBLK, 256, 0, stream>>>(deg, blk_off, row_start);
    hipMemsetAsync(cursor, 0, NN * sizeof(int), stream);
    k_csrfill<<<edge_blocks, 256, 0, stream>>>(head, tail, row_start, cursor, csr_tail);

    k_prep_te<<<node_blocks, 256, 0, stream>>>(ego_a, te_a);

    // (layer,t) schedule with fused flags; last scores pass of the net is dead.
    // (0,0): SCORES    (0,1): SCORES|OUT|NEXT    (1,0): SCORES    (1,1): OUT
    k_dinv<<<dinv_blocks, 256, 0, stream>>>(A4, row_start, d4);
    k_fused<<<wave_blocks, 256, 0, stream>>>(A4, d4, ego_a, row_start, csr_tail,
                                             te_a, A4, out, ego_b, te_b, FL_SCORES);
    k_dinv<<<dinv_blocks, 256, 0, stream>>>(A4, row_start, d4);
    k_fused<<<wave_blocks, 256, 0, stream>>>(A4, d4, ego_a, row_start, csr_tail,
                                             te_a, A4, out, ego_b, te_b,
                                             FL_SCORES | FL_OUT | FL_NEXT);
    k_dinv<<<dinv_blocks, 256, 0, stream>>>(A4, row_start, d4);
    k_fused<<<wave_blocks, 256, 0, stream>>>(A4, d4, ego_b, row_start, csr_tail,
                                             te_b, A4, out, ego_a, te_a, FL_SCORES);
    k_dinv<<<dinv_blocks, 256, 0, stream>>>(A4, row_start, d4);
    k_fused<<<wave_blocks, 256, 0, stream>>>(A4, d4, ego_b, row_start, csr_tail,
                                             te_b, A4, out, ego_a, te_a, FL_OUT);

    k_out<<<node_blocks, 256, 0, stream>>>(out, NN * DIM_);
}

// Round 6
// 827.014 us; speedup vs baseline: 3.1101x; 1.0439x over previous
//
#include <hip/hip_runtime.h>
#include <hip/hip_bf16.h>

// DGCF forward, MI355X. f32 in/out.
// R6: head-side d[n] dropped (l2norm is scale-invariant; d=0 <=> empty row <=> acc=0);
// softmax*d[tail] hoisted to edge-parallel k_vals (bf16); ego stored bf16;
// te(layer0) fused into k_init.
#define NUSER 50000
#define NITEM 50000
#define NN    100000          // NUSER+NITEM
#define NNZ_  1000000
#define DIM_  64
#define FK_   4
#define NBLK  391             // ceil_div(NN,256)

#define FL_SCORES 1
#define FL_OUT    2
#define FL_NEXT   4

static inline int ceil_div(int a, int b) { return (a + b - 1) / b; }

static __device__ inline float bf2f(unsigned short u) {
    return __uint_as_float(((unsigned int)u) << 16);
}
static __device__ inline unsigned short f2bf(float f) {
    unsigned int x = __float_as_uint(f);
    x += 0x7fffu + ((x >> 16) & 1u);
    return (unsigned short)(x >> 16);
}

// ego_bf = concat(user,item) as bf16; out = same in f32; te = tanh(l2norm chunk16).
__global__ void k_init(const float* __restrict__ eu, const float* __restrict__ ei,
                       unsigned short* __restrict__ egob, float* __restrict__ out,
                       unsigned short* __restrict__ te) {
    int i = blockIdx.x * 256 + threadIdx.x;
    if (i >= NN * DIM_) return;
    float v = (i < NUSER * DIM_) ? eu[i] : ei[i - NUSER * DIM_];
    egob[i] = f2bf(v);
    out[i] = v;
    float s = v * v;
    s += __shfl_xor(s, 1); s += __shfl_xor(s, 2);
    s += __shfl_xor(s, 4); s += __shfl_xor(s, 8);
    float nrm = v / fmaxf(sqrtf(s), 1e-12f);
    float ex = __expf(2.0f * nrm);
    te[i] = f2bf((ex - 1.0f) / (ex + 1.0f));
}

__global__ void k_initA(float4* __restrict__ A4) {
    int e = blockIdx.x * 256 + threadIdx.x;
    if (e < NNZ_) A4[e] = make_float4(1.0f, 1.0f, 1.0f, 1.0f);
}

// ---- CSR build (once per launch) ----
__global__ void k_hist(const int* __restrict__ head, int* __restrict__ deg) {
    int e = blockIdx.x * 256 + threadIdx.x;
    if (e < NNZ_) atomicAdd(&deg[head[e]], 1);
}

__global__ void k_blksum(const int* __restrict__ deg, int* __restrict__ partials) {
    __shared__ int sh[256];
    int i = blockIdx.x * 256 + threadIdx.x;
    sh[threadIdx.x] = (i < NN) ? deg[i] : 0;
    __syncthreads();
    for (int off = 128; off > 0; off >>= 1) {
        if (threadIdx.x < off) sh[threadIdx.x] += sh[threadIdx.x + off];
        __syncthreads();
    }
    if (threadIdx.x == 0) partials[blockIdx.x] = sh[0];
}

__global__ void k_scanp(const int* __restrict__ partials, int* __restrict__ blk_off,
                        int* __restrict__ row_start_end) {
    __shared__ int sh[512];
    int t = threadIdx.x;
    int v = (t < NBLK) ? partials[t] : 0;
    sh[t] = v;
    __syncthreads();
    for (int off = 1; off < 512; off <<= 1) {
        int u = 0;
        if (t >= off) u = sh[t - off];
        __syncthreads();
        sh[t] += u;
        __syncthreads();
    }
    if (t < NBLK) blk_off[t] = sh[t] - v;
    if (t == 511) row_start_end[0] = sh[511];
}

__global__ void k_fill(const int* __restrict__ deg, const int* __restrict__ blk_off,
                       int* __restrict__ row_start) {
    __shared__ int sh[256];
    int i = blockIdx.x * 256 + threadIdx.x;
    int v = (i < NN) ? deg[i] : 0;
    sh[threadIdx.x] = v;
    __syncthreads();
    for (int off = 1; off < 256; off <<= 1) {
        int u = 0;
        if (threadIdx.x >= off) u = sh[threadIdx.x - off];
        __syncthreads();
        sh[threadIdx.x] += u;
        __syncthreads();
    }
    if (i < NN) row_start[i] = blk_off[blockIdx.x] + sh[threadIdx.x] - v;
}

__global__ void k_csrfill(const int* __restrict__ head, const int* __restrict__ tail,
                          const int* __restrict__ row_start, int* __restrict__ cursor,
                          int* __restrict__ csr_tail) {
    int e = blockIdx.x * 256 + threadIdx.x;
    if (e >= NNZ_) return;
    int h = head[e];
    int pos = row_start[h] + atomicAdd(&cursor[h], 1);
    csr_tail[pos] = tail[e];
}

// ---- per iteration ----
// d4[n] = g(rowsum of softmax(A4) per factor); thread per node, streaming A4.
__global__ void k_dinv(const float4* __restrict__ A4, const int* __restrict__ row_start,
                       float4* __restrict__ d4) {
    int n = blockIdx.x * 256 + threadIdx.x;
    if (n >= NN) return;
    int r0 = row_start[n], r1 = row_start[n + 1];
    float s0 = 0.f, s1 = 0.f, s2 = 0.f, s3 = 0.f;
    for (int k = r0; k < r1; ++k) {
        float4 a = A4[k];
        float m = fmaxf(fmaxf(a.x, a.y), fmaxf(a.z, a.w));
        float e0 = __expf(a.x - m), e1 = __expf(a.y - m), e2 = __expf(a.z - m), e3 = __expf(a.w - m);
        float inv = 1.0f / (e0 + e1 + e2 + e3);
        s0 += e0 * inv; s1 += e1 * inv; s2 += e2 * inv; s3 += e3 * inv;
    }
    float4 d;
    d.x = (s0 > 0.f) ? 1.0f / sqrtf(fmaxf(s0, 1e-12f)) : 0.f;
    d.y = (s1 > 0.f) ? 1.0f / sqrtf(fmaxf(s1, 1e-12f)) : 0.f;
    d.z = (s2 > 0.f) ? 1.0f / sqrtf(fmaxf(s2, 1e-12f)) : 0.f;
    d.w = (s3 > 0.f) ? 1.0f / sqrtf(fmaxf(s3, 1e-12f)) : 0.f;
    d4[n] = d;
}

// Edge-parallel: vals[e][f] = softmax(A4[e])[f] * d4[tail[e]][f]  (bf16x4).
__global__ void k_vals(const float4* __restrict__ A4, const float4* __restrict__ d4,
                       const int* __restrict__ csr_tail, ushort4* __restrict__ vals) {
    int e = blockIdx.x * 256 + threadIdx.x;
    if (e >= NNZ_) return;
    float4 a = A4[e];
    float m = fmaxf(fmaxf(a.x, a.y), fmaxf(a.z, a.w));
    float e0 = __expf(a.x - m), e1 = __expf(a.y - m), e2 = __expf(a.z - m), e3 = __expf(a.w - m);
    float inv = 1.0f / (e0 + e1 + e2 + e3);
    float4 dt = d4[csr_tail[e]];
    ushort4 o;
    o.x = f2bf(e0 * inv * dt.x);
    o.y = f2bf(e1 * inv * dt.y);
    o.z = f2bf(e2 * inv * dt.z);
    o.w = f2bf(e3 * inv * dt.w);
    vals[e] = o;
}

// One wave per node. acc[j] = sum_k vals[k][f]*ego_bf[tail_k][j]; fn = chunk-l2norm(acc)
// (head-side d dropped: l2norm is scale-invariant, d=0 <=> acc=0).
// Optional: scores (A4 += dot16(fn, te[tail])), out-accumulate, next ego/te.
__global__ void k_fused(const unsigned short* __restrict__ vals,
                        const unsigned short* __restrict__ egob,
                        const int* __restrict__ row_start, const int* __restrict__ csr_tail,
                        const unsigned short* __restrict__ te,
                        float4* __restrict__ A4w,
                        float* __restrict__ out, unsigned short* __restrict__ egob_next,
                        unsigned short* __restrict__ te_next, int flags) {
    int n = (blockIdx.x * 256 + threadIdx.x) >> 6;
    if (n >= NN) return;
    int j = threadIdx.x & 63;
    int f = j >> 4;
    int r0 = row_start[n], r1 = row_start[n + 1];

    float acc = 0.0f;
    int k = r0;
    for (; k + 1 < r1; k += 2) {
        int t0 = csr_tail[k], t1 = csr_tail[k + 1];
        float v0 = bf2f(vals[(size_t)k * 4 + f]);
        float v1 = bf2f(vals[(size_t)(k + 1) * 4 + f]);
        float x0 = bf2f(egob[t0 * 64 + j]);
        float x1 = bf2f(egob[t1 * 64 + j]);
        acc += v0 * x0 + v1 * x1;
    }
    if (k < r1) {
        int t0 = csr_tail[k];
        acc += bf2f(vals[(size_t)k * 4 + f]) * bf2f(egob[t0 * 64 + j]);
    }

    float s = acc * acc;
    s += __shfl_xor(s, 1); s += __shfl_xor(s, 2);
    s += __shfl_xor(s, 4); s += __shfl_xor(s, 8);
    float fn = acc / fmaxf(sqrtf(s), 1e-12f);

    if (flags & FL_SCORES) {
        int k2 = r0;
        for (; k2 + 1 < r1; k2 += 2) {
            int t0 = csr_tail[k2], t1 = csr_tail[k2 + 1];
            float p0 = fn * bf2f(te[t0 * 64 + j]);
            float p1 = fn * bf2f(te[t1 * 64 + j]);
            p0 += __shfl_xor(p0, 1); p1 += __shfl_xor(p1, 1);
            p0 += __shfl_xor(p0, 2); p1 += __shfl_xor(p1, 2);
            p0 += __shfl_xor(p0, 4); p1 += __shfl_xor(p1, 4);
            p0 += __shfl_xor(p0, 8); p1 += __shfl_xor(p1, 8);
            if ((j & 15) == 0) {
                ((float*)(A4w + k2))[f] += p0;
                ((float*)(A4w + k2 + 1))[f] += p1;
            }
        }
        if (k2 < r1) {
            int t0 = csr_tail[k2];
            float p0 = fn * bf2f(te[t0 * 64 + j]);
            p0 += __shfl_xor(p0, 1); p0 += __shfl_xor(p0, 2);
            p0 += __shfl_xor(p0, 4); p0 += __shfl_xor(p0, 8);
            if ((j & 15) == 0) ((float*)(A4w + k2))[f] += p0;
        }
    }
    if (flags & FL_OUT) out[n * 64 + j] += fn;
    if (flags & FL_NEXT) {
        egob_next[n * 64 + j] = f2bf(fn);
        float ex = __expf(2.0f * fn);
        te_next[n * 64 + j] = f2bf((ex - 1.0f) / (ex + 1.0f));
    }
}

__global__ void k_out(float* __restrict__ out, int nelem) {
    int i = blockIdx.x * 256 + threadIdx.x;
    if (i < nelem) out[i] *= (1.0f / 3.0f);
}

extern "C" void kernel_launch(void* const* d_in, const int* in_sizes, int n_in,
                              void* d_out, int out_size, void* d_ws, size_t ws_size,
                              hipStream_t stream) {
    const float* eu = (const float*)d_in[0];
    const float* ei = (const float*)d_in[1];
    const int* head = (const int*)d_in[2];
    const int* tail = (const int*)d_in[3];
    float* out = (float*)d_out;   // 3-term accumulator, scaled at the end

    // workspace layout — ~83 MB
    unsigned short* ego_a = (unsigned short*)d_ws;          // 12.8 MB
    unsigned short* ego_b = ego_a + (size_t)NN * DIM_;      // 12.8 MB
    unsigned short* te_a  = ego_b + (size_t)NN * DIM_;      // 12.8 MB
    unsigned short* te_b  = te_a + (size_t)NN * DIM_;       // 12.8 MB
    float4* A4 = (float4*)(te_b + (size_t)NN * DIM_);       // 16 MB
    float4* d4 = A4 + (size_t)NNZ_;                         // 1.6 MB
    ushort4* vals = (ushort4*)(d4 + NN);                    // 8 MB
    int* row_start = (int*)(vals + NNZ_);                   // NN+1
    int* deg    = row_start + (NN + 1);                     // NN
    int* cursor = deg + NN;                                 // NN
    int* csr_tail = cursor + NN;                            // 4 MB
    int* partials = csr_tail + NNZ_;                        // NBLK
    int* blk_off  = partials + NBLK;                        // NBLK

    const int node_blocks = ceil_div(NN * DIM_, 256);      // 25000
    const int edge_blocks = ceil_div(NNZ_, 256);           // 3907
    const int wave_blocks = ceil_div(NN * 64, 256);        // 25000
    const int dinv_blocks = ceil_div(NN, 256);             // 391

    k_init<<<node_blocks, 256, 0, stream>>>(eu, ei, ego_a, out, te_a);
    k_initA<<<edge_blocks, 256, 0, stream>>>(A4);

    // CSR build (graph constant within a launch)
    hipMemsetAsync(deg, 0, NN * sizeof(int), stream);
    k_hist<<<edge_blocks, 256, 0, stream>>>(head, deg);
    k_blksum<<<NBLK, 256, 0, stream>>>(deg, partials);
    k_scanp<<<1, 512, 0, stream>>>(partials, blk_off, &row_start[NN]);
    k_fill<<<NBLK, 256, 0, stream>>>(deg, blk_off, row_start);
    hipMemsetAsync(cursor, 0, NN * sizeof(int), stream);
    k_csrfill<<<edge_blocks, 256, 0, stream>>>(head, tail, row_start, cursor, csr_tail);

    // (layer,t) schedule; last scores pass of the net is dead.
    // (0,0): SCORES    (0,1): SCORES|OUT|NEXT    (1,0): SCORES    (1,1): OUT
    const int fl[4] = { FL_SCORES, FL_SCORES | FL_OUT | FL_NEXT, FL_SCORES, FL_OUT };
    const unsigned short* egos[4] = { ego_a, ego_a, ego_b, ego_b };
    const unsigned short* tes[4]  = { te_a,  te_a,  te_b,  te_b };
    unsigned short* egon[4] = { ego_b, ego_b, ego_a, ego_a };
    unsigned short* ten[4]  = { te_b,  te_b,  te_a,  te_a };
    for (int it = 0; it < 4; ++it) {
        k_dinv<<<dinv_blocks, 256, 0, stream>>>(A4, row_start, d4);
        k_vals<<<edge_blocks, 256, 0, stream>>>(A4, d4, csr_tail, vals);
        k_fused<<<wave_blocks, 256, 0, stream>>>((const unsigned short*)vals, egos[it],
                                                 row_start, csr_tail, tes[it], A4,
                                                 out, egon[it], ten[it], fl[it]);
    }
    k_out<<<node_blocks, 256, 0, stream>>>(out, NN * DIM_);
}

// Round 7
// 676.624 us; speedup vs baseline: 3.8014x; 1.2223x over previous
//
#include <hip/hip_runtime.h>
#include <hip/hip_bf16.h>

// DGCF forward, MI355X. f32 in/out.
// R7: one mega-kernel per iteration. Scores walk also computes A_new, softmax
// (1 exp/lane + xor16/32 cross-group sum; no max-sub — A bounded in [-2,4]),
// stores svals bf16, accumulates rowsum in regs -> d4_next (ping-pong).
// k_dinv / k_vals / k_initA eliminated. Unroll-4 walk1, unroll-2 walk2.
#define NUSER 50000
#define NITEM 50000
#define NN    100000          // NUSER+NITEM
#define NNZ_  1000000
#define DIM_  64
#define NBLK  391             // ceil_div(NN,256)

#define FL_SVC    1   // svals == 0.25 (iteration 0)
#define FL_SCORES 2   // do walk2 (scores + softmax + d4_next)
#define FL_OUT    4   // out += fn
#define FL_NEXT   8   // write ego_next / te_next
#define FL_ACONST 16  // A_old == 1 (iteration 0)
#define FL_ASTORE 32  // store A_new
#define FL_FIN    64  // out = (out + fn) / 3

static inline int ceil_div(int a, int b) { return (a + b - 1) / b; }

static __device__ inline float bf2f(unsigned short u) {
    return __uint_as_float(((unsigned int)u) << 16);
}
static __device__ inline unsigned short f2bf(float f) {
    unsigned int x = __float_as_uint(f);
    x += 0x7fffu + ((x >> 16) & 1u);
    return (unsigned short)(x >> 16);
}

// ego_bf = concat(user,item) bf16; out = same f32; te = tanh(l2norm chunk16).
__global__ void k_init(const float* __restrict__ eu, const float* __restrict__ ei,
                       unsigned short* __restrict__ egob, float* __restrict__ out,
                       unsigned short* __restrict__ te) {
    int i = blockIdx.x * 256 + threadIdx.x;
    if (i >= NN * DIM_) return;
    float v = (i < NUSER * DIM_) ? eu[i] : ei[i - NUSER * DIM_];
    egob[i] = f2bf(v);
    out[i] = v;
    float s = v * v;
    s += __shfl_xor(s, 1); s += __shfl_xor(s, 2);
    s += __shfl_xor(s, 4); s += __shfl_xor(s, 8);
    float nrm = v / fmaxf(sqrtf(s), 1e-12f);
    float ex = __expf(2.0f * nrm);
    te[i] = f2bf((ex - 1.0f) / (ex + 1.0f));
}

// ---- CSR build (once per launch) ----
__global__ void k_hist(const int* __restrict__ head, int* __restrict__ deg) {
    int e = blockIdx.x * 256 + threadIdx.x;
    if (e < NNZ_) atomicAdd(&deg[head[e]], 1);
}

__global__ void k_blksum(const int* __restrict__ deg, int* __restrict__ partials) {
    __shared__ int sh[256];
    int i = blockIdx.x * 256 + threadIdx.x;
    sh[threadIdx.x] = (i < NN) ? deg[i] : 0;
    __syncthreads();
    for (int off = 128; off > 0; off >>= 1) {
        if (threadIdx.x < off) sh[threadIdx.x] += sh[threadIdx.x + off];
        __syncthreads();
    }
    if (threadIdx.x == 0) partials[blockIdx.x] = sh[0];
}

__global__ void k_scanp(const int* __restrict__ partials, int* __restrict__ blk_off,
                        int* __restrict__ row_start_end) {
    __shared__ int sh[512];
    int t = threadIdx.x;
    int v = (t < NBLK) ? partials[t] : 0;
    sh[t] = v;
    __syncthreads();
    for (int off = 1; off < 512; off <<= 1) {
        int u = 0;
        if (t >= off) u = sh[t - off];
        __syncthreads();
        sh[t] += u;
        __syncthreads();
    }
    if (t < NBLK) blk_off[t] = sh[t] - v;
    if (t == 511) row_start_end[0] = sh[511];
}

// row_start fill + d4_0 seed: rowsum_0 = 0.25*deg -> d4_0 = 2/sqrt(deg) (0 if deg=0).
__global__ void k_fill(const int* __restrict__ deg, const int* __restrict__ blk_off,
                       int* __restrict__ row_start, float4* __restrict__ d4a) {
    __shared__ int sh[256];
    int i = blockIdx.x * 256 + threadIdx.x;
    int v = (i < NN) ? deg[i] : 0;
    sh[threadIdx.x] = v;
    __syncthreads();
    for (int off = 1; off < 256; off <<= 1) {
        int u = 0;
        if (threadIdx.x >= off) u = sh[threadIdx.x - off];
        __syncthreads();
        sh[threadIdx.x] += u;
        __syncthreads();
    }
    if (i < NN) {
        row_start[i] = blk_off[blockIdx.x] + sh[threadIdx.x] - v;
        float dd = (v > 0) ? 2.0f / sqrtf((float)v) : 0.0f;
        d4a[i] = make_float4(dd, dd, dd, dd);
    }
}

__global__ void k_csrfill(const int* __restrict__ head, const int* __restrict__ tail,
                          const int* __restrict__ row_start, int* __restrict__ cursor,
                          int* __restrict__ csr_tail) {
    int e = blockIdx.x * 256 + threadIdx.x;
    if (e >= NNZ_) return;
    int h = head[e];
    int pos = row_start[h] + atomicAdd(&cursor[h], 1);
    csr_tail[pos] = tail[e];
}

// ---- the per-iteration mega-kernel (one wave per node) ----
// walk1: acc[j] = sum_k svals[k][f]*d4c[tail][f]*ego[tail][j]; fn = chunk-l2norm(acc)
//        (head-side d dropped: l2norm scale-invariant; d=0 <=> acc=0).
// walk2 (FL_SCORES): p = dot16(fn, te[tail]); A_new = A_old + p; softmax over factors
//        (own-factor exp + xor16/32 sum); svals[k] = bf16(sval); rowsum in regs;
//        d4n[n] written at row end.
template<int FLAGS>
__global__ void k_iter(unsigned short* __restrict__ svals,      // bf16 [NNZ*4] CSR
                       const float* __restrict__ d4c,           // f32 [NN*4] cur
                       float* __restrict__ d4n,                 // f32 [NN*4] next
                       const unsigned short* __restrict__ egob,
                       const unsigned short* __restrict__ te,
                       const int* __restrict__ row_start, const int* __restrict__ csr_tail,
                       float* __restrict__ A4,                  // f32 [NNZ*4] CSR
                       float* __restrict__ out,
                       unsigned short* __restrict__ egon, unsigned short* __restrict__ ten) {
    int n = (blockIdx.x * 256 + threadIdx.x) >> 6;
    if (n >= NN) return;
    int j = threadIdx.x & 63;
    int f = j >> 4;
    int r0 = row_start[n], r1 = row_start[n + 1];

    // ---- walk1 (unroll 4) ----
    float acc = 0.0f;
    int k = r0;
    for (; k + 3 < r1; k += 4) {
        int t0 = csr_tail[k], t1 = csr_tail[k + 1], t2 = csr_tail[k + 2], t3 = csr_tail[k + 3];
        float w0, w1, w2, w3;
        if (FLAGS & FL_SVC) { w0 = w1 = w2 = w3 = 0.25f; }
        else {
            w0 = bf2f(svals[k * 4 + f]);       w1 = bf2f(svals[(k + 1) * 4 + f]);
            w2 = bf2f(svals[(k + 2) * 4 + f]); w3 = bf2f(svals[(k + 3) * 4 + f]);
        }
        w0 *= d4c[t0 * 4 + f]; w1 *= d4c[t1 * 4 + f];
        w2 *= d4c[t2 * 4 + f]; w3 *= d4c[t3 * 4 + f];
        acc += w0 * bf2f(egob[t0 * 64 + j]) + w1 * bf2f(egob[t1 * 64 + j])
             + w2 * bf2f(egob[t2 * 64 + j]) + w3 * bf2f(egob[t3 * 64 + j]);
    }
    for (; k < r1; ++k) {
        int t = csr_tail[k];
        float w = (FLAGS & FL_SVC) ? 0.25f : bf2f(svals[k * 4 + f]);
        acc += w * d4c[t * 4 + f] * bf2f(egob[t * 64 + j]);
    }

    float s = acc * acc;
    s += __shfl_xor(s, 1); s += __shfl_xor(s, 2);
    s += __shfl_xor(s, 4); s += __shfl_xor(s, 8);
    float fn = acc / fmaxf(sqrtf(s), 1e-12f);

    if (FLAGS & FL_FIN)      out[n * 64 + j] = (out[n * 64 + j] + fn) * (1.0f / 3.0f);
    else if (FLAGS & FL_OUT) out[n * 64 + j] += fn;
    if (FLAGS & FL_NEXT) {
        egon[n * 64 + j] = f2bf(fn);
        float ex = __expf(2.0f * fn);
        ten[n * 64 + j] = f2bf((ex - 1.0f) / (ex + 1.0f));
    }

    // ---- walk2 (unroll 2) ----
    if (FLAGS & FL_SCORES) {
        float rs = 0.0f;
        bool wlane = ((j & 15) == 0);
        int k2 = r0;
        for (; k2 + 1 < r1; k2 += 2) {
            int t0 = csr_tail[k2], t1 = csr_tail[k2 + 1];
            float p0 = fn * bf2f(te[t0 * 64 + j]);
            float p1 = fn * bf2f(te[t1 * 64 + j]);
            p0 += __shfl_xor(p0, 1); p1 += __shfl_xor(p1, 1);
            p0 += __shfl_xor(p0, 2); p1 += __shfl_xor(p1, 2);
            p0 += __shfl_xor(p0, 4); p1 += __shfl_xor(p1, 4);
            p0 += __shfl_xor(p0, 8); p1 += __shfl_xor(p1, 8);
            float a0 = (FLAGS & FL_ACONST) ? 1.0f : A4[k2 * 4 + f];
            float a1 = (FLAGS & FL_ACONST) ? 1.0f : A4[(k2 + 1) * 4 + f];
            a0 += p0; a1 += p1;
            if ((FLAGS & FL_ASTORE) && wlane) {
                A4[k2 * 4 + f] = a0;
                A4[(k2 + 1) * 4 + f] = a1;
            }
            float e0 = __expf(a0), e1 = __expf(a1);
            float den0 = e0, den1 = e1;
            den0 += __shfl_xor(den0, 16); den1 += __shfl_xor(den1, 16);
            den0 += __shfl_xor(den0, 32); den1 += __shfl_xor(den1, 32);
            float sv0 = e0 / den0, sv1 = e1 / den1;
            rs += sv0 + sv1;
            if (wlane) {
                svals[k2 * 4 + f] = f2bf(sv0);
                svals[(k2 + 1) * 4 + f] = f2bf(sv1);
            }
        }
        if (k2 < r1) {
            int t0 = csr_tail[k2];
            float p0 = fn * bf2f(te[t0 * 64 + j]);
            p0 += __shfl_xor(p0, 1); p0 += __shfl_xor(p0, 2);
            p0 += __shfl_xor(p0, 4); p0 += __shfl_xor(p0, 8);
            float a0 = (FLAGS & FL_ACONST) ? 1.0f : A4[k2 * 4 + f];
            a0 += p0;
            if ((FLAGS & FL_ASTORE) && wlane) A4[k2 * 4 + f] = a0;
            float e0 = __expf(a0);
            float den0 = e0;
            den0 += __shfl_xor(den0, 16);
            den0 += __shfl_xor(den0, 32);
            float sv0 = e0 / den0;
            rs += sv0;
            if (wlane) svals[k2 * 4 + f] = f2bf(sv0);
        }
        if (wlane) d4n[n * 4 + f] = (rs > 0.0f) ? 1.0f / sqrtf(fmaxf(rs, 1e-12f)) : 0.0f;
    }
}

extern "C" void kernel_launch(void* const* d_in, const int* in_sizes, int n_in,
                              void* d_out, int out_size, void* d_ws, size_t ws_size,
                              hipStream_t stream) {
    const float* eu = (const float*)d_in[0];
    const float* ei = (const float*)d_in[1];
    const int* head = (const int*)d_in[2];
    const int* tail = (const int*)d_in[3];
    float* out = (float*)d_out;   // 3-term accumulator, scaled at it3 (FL_FIN)

    // workspace layout — ~83 MB (16B-aligned types first)
    float* A4 = (float*)d_ws;                               // 1M f32x4  (16 MB)
    float* d4a = A4 + (size_t)NNZ_ * 4;                     // NN f32x4  (1.6 MB)
    float* d4b = d4a + (size_t)NN * 4;                      // NN f32x4  (1.6 MB)
    unsigned short* svals = (unsigned short*)(d4b + (size_t)NN * 4);  // 1M bf16x4 (8 MB)
    unsigned short* ego_a = svals + (size_t)NNZ_ * 4;       // 12.8 MB
    unsigned short* ego_b = ego_a + (size_t)NN * DIM_;      // 12.8 MB
    unsigned short* te_a  = ego_b + (size_t)NN * DIM_;      // 12.8 MB
    unsigned short* te_b  = te_a + (size_t)NN * DIM_;       // 12.8 MB
    int* row_start = (int*)(te_b + (size_t)NN * DIM_);      // NN+1
    int* deg    = row_start + (NN + 1);                     // NN
    int* cursor = deg + NN;                                 // NN
    int* csr_tail = cursor + NN;                            // 4 MB
    int* partials = csr_tail + NNZ_;                        // NBLK
    int* blk_off  = partials + NBLK;                        // NBLK

    const int node_blocks = ceil_div(NN * DIM_, 256);      // 25000
    const int edge_blocks = ceil_div(NNZ_, 256);           // 3907
    const int wave_blocks = ceil_div(NN * 64, 256);        // 25000

    k_init<<<node_blocks, 256, 0, stream>>>(eu, ei, ego_a, out, te_a);

    // CSR build (graph constant within a launch) + d4_0 seed
    hipMemsetAsync(deg, 0, NN * sizeof(int), stream);
    k_hist<<<edge_blocks, 256, 0, stream>>>(head, deg);
    k_blksum<<<NBLK, 256, 0, stream>>>(deg, partials);
    k_scanp<<<1, 512, 0, stream>>>(partials, blk_off, &row_start[NN]);
    k_fill<<<NBLK, 256, 0, stream>>>(deg, blk_off, row_start, (float4*)d4a);
    hipMemsetAsync(cursor, 0, NN * sizeof(int), stream);
    k_csrfill<<<edge_blocks, 256, 0, stream>>>(head, tail, row_start, cursor, csr_tail);

    // it0 = (0,0): svals==0.25, A_old==1; store A_1; -> svals_1, d4_1(b)
    k_iter<FL_SVC | FL_SCORES | FL_ACONST | FL_ASTORE>
        <<<wave_blocks, 256, 0, stream>>>(svals, d4a, d4b, ego_a, te_a,
                                          row_start, csr_tail, A4, out, ego_b, te_b);
    // it1 = (0,1): RMW A; layer-0 output (OUT) + next ego/te; -> svals_2, d4_2(a)
    k_iter<FL_SCORES | FL_ASTORE | FL_OUT | FL_NEXT>
        <<<wave_blocks, 256, 0, stream>>>(svals, d4b, d4a, ego_a, te_a,
                                          row_start, csr_tail, A4, out, ego_b, te_b);
    // it2 = (1,0): read A_2; A_3 store dead; -> svals_3, d4_3(b)
    k_iter<FL_SCORES>
        <<<wave_blocks, 256, 0, stream>>>(svals, d4a, d4b, ego_b, te_b,
                                          row_start, csr_tail, A4, out, ego_a, te_a);
    // it3 = (1,1): no scores (dead); final out = (out+fn)/3
    k_iter<FL_OUT | FL_FIN>
        <<<wave_blocks, 256, 0, stream>>>(svals, d4b, d4a, ego_b, te_b,
                                          row_start, csr_tail, A4, out, ego_a, te_a);
}

// Round 8
// 600.668 us; speedup vs baseline: 4.2821x; 1.1265x over previous
//
#include <hip/hip_runtime.h>
#include <hip/hip_bf16.h>

// DGCF forward, MI355X. f32 in/out.
// R8: (1) wave-uniform row walk scalarized via readfirstlane -> s_load csr_tail,
// SALU addressing; (2) ego+te interleaved as ushort2 per (node,dim) so walk2's
// te gather hits the cache line walk1 just fetched.
#define NUSER 50000
#define NITEM 50000
#define NN    100000          // NUSER+NITEM
#define NNZ_  1000000
#define DIM_  64
#define NBLK  391             // ceil_div(NN,256)

#define FL_SVC    1   // svals == 0.25 (iteration 0)
#define FL_SCORES 2   // do walk2 (scores + softmax + d4_next)
#define FL_OUT    4   // out += fn
#define FL_NEXT   8   // write egote_next
#define FL_ACONST 16  // A_old == 1 (iteration 0)
#define FL_ASTORE 32  // store A_new
#define FL_FIN    64  // out = (out + fn) / 3

static inline int ceil_div(int a, int b) { return (a + b - 1) / b; }

static __device__ inline float bf2f(unsigned short u) {
    return __uint_as_float(((unsigned int)u) << 16);
}
static __device__ inline unsigned short f2bf(float f) {
    unsigned int x = __float_as_uint(f);
    x += 0x7fffu + ((x >> 16) & 1u);
    return (unsigned short)(x >> 16);
}

// egote = {bf16(ego), bf16(tanh(l2norm chunk16(ego)))}; out = ego f32.
__global__ void k_init(const float* __restrict__ eu, const float* __restrict__ ei,
                       ushort2* __restrict__ egote, float* __restrict__ out) {
    int i = blockIdx.x * 256 + threadIdx.x;
    if (i >= NN * DIM_) return;
    float v = (i < NUSER * DIM_) ? eu[i] : ei[i - NUSER * DIM_];
    out[i] = v;
    float s = v * v;
    s += __shfl_xor(s, 1); s += __shfl_xor(s, 2);
    s += __shfl_xor(s, 4); s += __shfl_xor(s, 8);
    float nrm = v / fmaxf(sqrtf(s), 1e-12f);
    float ex = __expf(2.0f * nrm);
    ushort2 o;
    o.x = f2bf(v);
    o.y = f2bf((ex - 1.0f) / (ex + 1.0f));
    egote[i] = o;
}

// ---- CSR build (once per launch) ----
__global__ void k_hist(const int* __restrict__ head, int* __restrict__ deg) {
    int e = blockIdx.x * 256 + threadIdx.x;
    if (e < NNZ_) atomicAdd(&deg[head[e]], 1);
}

__global__ void k_blksum(const int* __restrict__ deg, int* __restrict__ partials) {
    __shared__ int sh[256];
    int i = blockIdx.x * 256 + threadIdx.x;
    sh[threadIdx.x] = (i < NN) ? deg[i] : 0;
    __syncthreads();
    for (int off = 128; off > 0; off >>= 1) {
        if (threadIdx.x < off) sh[threadIdx.x] += sh[threadIdx.x + off];
        __syncthreads();
    }
    if (threadIdx.x == 0) partials[blockIdx.x] = sh[0];
}

__global__ void k_scanp(const int* __restrict__ partials, int* __restrict__ blk_off,
                        int* __restrict__ row_start_end) {
    __shared__ int sh[512];
    int t = threadIdx.x;
    int v = (t < NBLK) ? partials[t] : 0;
    sh[t] = v;
    __syncthreads();
    for (int off = 1; off < 512; off <<= 1) {
        int u = 0;
        if (t >= off) u = sh[t - off];
        __syncthreads();
        sh[t] += u;
        __syncthreads();
    }
    if (t < NBLK) blk_off[t] = sh[t] - v;
    if (t == 511) row_start_end[0] = sh[511];
}

// row_start fill + d4_0 seed: rowsum_0 = 0.25*deg -> d4_0 = 2/sqrt(deg) (0 if deg=0).
__global__ void k_fill(const int* __restrict__ deg, const int* __restrict__ blk_off,
                       int* __restrict__ row_start, float4* __restrict__ d4a) {
    __shared__ int sh[256];
    int i = blockIdx.x * 256 + threadIdx.x;
    int v = (i < NN) ? deg[i] : 0;
    sh[threadIdx.x] = v;
    __syncthreads();
    for (int off = 1; off < 256; off <<= 1) {
        int u = 0;
        if (threadIdx.x >= off) u = sh[threadIdx.x - off];
        __syncthreads();
        sh[threadIdx.x] += u;
        __syncthreads();
    }
    if (i < NN) {
        row_start[i] = blk_off[blockIdx.x] + sh[threadIdx.x] - v;
        float dd = (v > 0) ? 2.0f / sqrtf((float)v) : 0.0f;
        d4a[i] = make_float4(dd, dd, dd, dd);
    }
}

__global__ void k_csrfill(const int* __restrict__ head, const int* __restrict__ tail,
                          const int* __restrict__ row_start, int* __restrict__ cursor,
                          int* __restrict__ csr_tail) {
    int e = blockIdx.x * 256 + threadIdx.x;
    if (e >= NNZ_) return;
    int h = head[e];
    int pos = row_start[h] + atomicAdd(&cursor[h], 1);
    csr_tail[pos] = tail[e];
}

// ---- per-iteration mega-kernel (one wave per node) ----
// walk1: acc[j] = sum_k svals[k][f]*d4c[tail][f]*ego[tail][j]; fn = chunk-l2norm(acc).
// walk2 (FL_SCORES): p = dot16(fn, te[tail]); A_new = A_old + p; softmax over factors
// (own-factor exp + xor16/32 sum); svals bf16; rowsum in regs -> d4n[n].
template<int FLAGS>
__global__ void k_iter(unsigned short* __restrict__ svals,      // bf16 [NNZ*4] CSR
                       const float* __restrict__ d4c,           // f32 [NN*4] cur
                       float* __restrict__ d4n,                 // f32 [NN*4] next
                       const ushort2* __restrict__ egote,       // {ego,te} bf16 [NN*64]
                       const int* __restrict__ row_start, const int* __restrict__ csr_tail,
                       float* __restrict__ A4,                  // f32 [NNZ*4] CSR
                       float* __restrict__ out,
                       ushort2* __restrict__ egoten) {
    int n = (blockIdx.x * 256 + threadIdx.x) >> 6;
    if (n >= NN) return;
    int j = threadIdx.x & 63;
    int f = j >> 4;
    // n is wave-uniform (one 64-lane wave per node) -> force scalar row bounds so
    // the k-loop, csr_tail loads, and t-addressing land on the scalar pipe.
    int r0 = __builtin_amdgcn_readfirstlane(row_start[n]);
    int r1 = __builtin_amdgcn_readfirstlane(row_start[n + 1]);

    // ---- walk1 (unroll 4) ----
    float acc = 0.0f;
    int k = r0;
    for (; k + 3 < r1; k += 4) {
        int t0 = csr_tail[k], t1 = csr_tail[k + 1], t2 = csr_tail[k + 2], t3 = csr_tail[k + 3];
        float w0, w1, w2, w3;
        if (FLAGS & FL_SVC) { w0 = w1 = w2 = w3 = 0.25f; }
        else {
            w0 = bf2f(svals[k * 4 + f]);       w1 = bf2f(svals[(k + 1) * 4 + f]);
            w2 = bf2f(svals[(k + 2) * 4 + f]); w3 = bf2f(svals[(k + 3) * 4 + f]);
        }
        w0 *= d4c[t0 * 4 + f]; w1 *= d4c[t1 * 4 + f];
        w2 *= d4c[t2 * 4 + f]; w3 *= d4c[t3 * 4 + f];
        acc += w0 * bf2f(egote[t0 * 64 + j].x) + w1 * bf2f(egote[t1 * 64 + j].x)
             + w2 * bf2f(egote[t2 * 64 + j].x) + w3 * bf2f(egote[t3 * 64 + j].x);
    }
    for (; k < r1; ++k) {
        int t = csr_tail[k];
        float w = (FLAGS & FL_SVC) ? 0.25f : bf2f(svals[k * 4 + f]);
        acc += w * d4c[t * 4 + f] * bf2f(egote[t * 64 + j].x);
    }

    float s = acc * acc;
    s += __shfl_xor(s, 1); s += __shfl_xor(s, 2);
    s += __shfl_xor(s, 4); s += __shfl_xor(s, 8);
    float fn = acc / fmaxf(sqrtf(s), 1e-12f);

    if (FLAGS & FL_FIN)      out[n * 64 + j] = (out[n * 64 + j] + fn) * (1.0f / 3.0f);
    else if (FLAGS & FL_OUT) out[n * 64 + j] += fn;
    if (FLAGS & FL_NEXT) {
        float ex = __expf(2.0f * fn);
        ushort2 o;
        o.x = f2bf(fn);
        o.y = f2bf((ex - 1.0f) / (ex + 1.0f));
        egoten[n * 64 + j] = o;
    }

    // ---- walk2 (unroll 2); te gathers hit the lines walk1 just fetched ----
    if (FLAGS & FL_SCORES) {
        float rs = 0.0f;
        bool wlane = ((j & 15) == 0);
        int k2 = r0;
        for (; k2 + 1 < r1; k2 += 2) {
            int t0 = csr_tail[k2], t1 = csr_tail[k2 + 1];
            float p0 = fn * bf2f(egote[t0 * 64 + j].y);
            float p1 = fn * bf2f(egote[t1 * 64 + j].y);
            p0 += __shfl_xor(p0, 1); p1 += __shfl_xor(p1, 1);
            p0 += __shfl_xor(p0, 2); p1 += __shfl_xor(p1, 2);
            p0 += __shfl_xor(p0, 4); p1 += __shfl_xor(p1, 4);
            p0 += __shfl_xor(p0, 8); p1 += __shfl_xor(p1, 8);
            float a0 = (FLAGS & FL_ACONST) ? 1.0f : A4[k2 * 4 + f];
            float a1 = (FLAGS & FL_ACONST) ? 1.0f : A4[(k2 + 1) * 4 + f];
            a0 += p0; a1 += p1;
            if ((FLAGS & FL_ASTORE) && wlane) {
                A4[k2 * 4 + f] = a0;
                A4[(k2 + 1) * 4 + f] = a1;
            }
            float e0 = __expf(a0), e1 = __expf(a1);
            float den0 = e0, den1 = e1;
            den0 += __shfl_xor(den0, 16); den1 += __shfl_xor(den1, 16);
            den0 += __shfl_xor(den0, 32); den1 += __shfl_xor(den1, 32);
            float sv0 = e0 / den0, sv1 = e1 / den1;
            rs += sv0 + sv1;
            if (wlane) {
                svals[k2 * 4 + f] = f2bf(sv0);
                svals[(k2 + 1) * 4 + f] = f2bf(sv1);
            }
        }
        if (k2 < r1) {
            int t0 = csr_tail[k2];
            float p0 = fn * bf2f(egote[t0 * 64 + j].y);
            p0 += __shfl_xor(p0, 1); p0 += __shfl_xor(p0, 2);
            p0 += __shfl_xor(p0, 4); p0 += __shfl_xor(p0, 8);
            float a0 = (FLAGS & FL_ACONST) ? 1.0f : A4[k2 * 4 + f];
            a0 += p0;
            if ((FLAGS & FL_ASTORE) && wlane) A4[k2 * 4 + f] = a0;
            float e0 = __expf(a0);
            float den0 = e0;
            den0 += __shfl_xor(den0, 16);
            den0 += __shfl_xor(den0, 32);
            float sv0 = e0 / den0;
            rs += sv0;
            if (wlane) svals[k2 * 4 + f] = f2bf(sv0);
        }
        if (wlane) d4n[n * 4 + f] = (rs > 0.0f) ? 1.0f / sqrtf(fmaxf(rs, 1e-12f)) : 0.0f;
    }
}

extern "C" void kernel_launch(void* const* d_in, const int* in_sizes, int n_in,
                              void* d_out, int out_size, void* d_ws, size_t ws_size,
                              hipStream_t stream) {
    const float* eu = (const float*)d_in[0];
    const float* ei = (const float*)d_in[1];
    const int* head = (const int*)d_in[2];
    const int* tail = (const int*)d_in[3];
    float* out = (float*)d_out;   // 3-term accumulator, scaled at it3 (FL_FIN)

    // workspace layout — ~83 MB (16B-aligned types first)
    float* A4 = (float*)d_ws;                               // 1M f32x4  (16 MB)
    float* d4a = A4 + (size_t)NNZ_ * 4;                     // NN f32x4  (1.6 MB)
    float* d4b = d4a + (size_t)NN * 4;                      // NN f32x4  (1.6 MB)
    unsigned short* svals = (unsigned short*)(d4b + (size_t)NN * 4);  // 1M bf16x4 (8 MB)
    ushort2* egote_a = (ushort2*)(svals + (size_t)NNZ_ * 4);// NN*64 u2  (25.6 MB)
    ushort2* egote_b = egote_a + (size_t)NN * DIM_;         // 25.6 MB
    int* row_start = (int*)(egote_b + (size_t)NN * DIM_);   // NN+1
    int* deg    = row_start + (NN + 1);                     // NN
    int* cursor = deg + NN;                                 // NN
    int* csr_tail = cursor + NN;                            // 4 MB
    int* partials = csr_tail + NNZ_;                        // NBLK
    int* blk_off  = partials + NBLK;                        // NBLK

    const int node_blocks = ceil_div(NN * DIM_, 256);      // 25000
    const int edge_blocks = ceil_div(NNZ_, 256);           // 3907
    const int wave_blocks = ceil_div(NN * 64, 256);        // 25000

    k_init<<<node_blocks, 256, 0, stream>>>(eu, ei, egote_a, out);

    // CSR build (graph constant within a launch) + d4_0 seed
    hipMemsetAsync(deg, 0, NN * sizeof(int), stream);
    k_hist<<<edge_blocks, 256, 0, stream>>>(head, deg);
    k_blksum<<<NBLK, 256, 0, stream>>>(deg, partials);
    k_scanp<<<1, 512, 0, stream>>>(partials, blk_off, &row_start[NN]);
    k_fill<<<NBLK, 256, 0, stream>>>(deg, blk_off, row_start, (float4*)d4a);
    hipMemsetAsync(cursor, 0, NN * sizeof(int), stream);
    k_csrfill<<<edge_blocks, 256, 0, stream>>>(head, tail, row_start, cursor, csr_tail);

    // it0 = (0,0): svals==0.25, A_old==1; store A_1; -> svals_1, d4_1(b)
    k_iter<FL_SVC | FL_SCORES | FL_ACONST | FL_ASTORE>
        <<<wave_blocks, 256, 0, stream>>>(svals, d4a, d4b, egote_a,
                                          row_start, csr_tail, A4, out, egote_b);
    // it1 = (0,1): RMW A; layer-0 output (OUT) + next egote; -> svals_2, d4_2(a)
    k_iter<FL_SCORES | FL_ASTORE | FL_OUT | FL_NEXT>
        <<<wave_blocks, 256, 0, stream>>>(svals, d4b, d4a, egote_a,
                                          row_start, csr_tail, A4, out, egote_b);
    // it2 = (1,0): read A_2; A_3 store dead; -> svals_3, d4_3(b)
    k_iter<FL_SCORES>
        <<<wave_blocks, 256, 0, stream>>>(svals, d4a, d4b, egote_b,
                                          row_start, csr_tail, A4, out, egote_a);
    // it3 = (1,1): no scores (dead); final out = (out+fn)/3
    k_iter<FL_OUT | FL_FIN>
        <<<wave_blocks, 256, 0, stream>>>(svals, d4b, d4a, egote_b,
                                          row_start, csr_tail, A4, out, egote_a);
}

// Round 9
// 518.204 us; speedup vs baseline: 4.9636x; 1.1591x over previous
//
#include <hip/hip_runtime.h>
#include <hip/hip_bf16.h>

// DGCF forward, MI355X. f32 in/out.
// R9: scores/softmax moved to edge-parallel k_scores_edge (1 thread/edge, no
// cross-lane ops — kills walk2's 6M ds_swizzle LDS-pipe serialization).
// k_iter = walk1 only (wave/node). k_dinv2 = rowsum from svals (thread/node).
// ego/te de-interleaved (walk1 gathers 2 B/lane again).
#define NUSER 50000
#define NITEM 50000
#define NN    100000          // NUSER+NITEM
#define NNZ_  1000000
#define DIM_  64
#define NBLK  391             // ceil_div(NN,256)

#define FL_SVC    1   // svals == 0.25 (iteration 0)
#define FL_FN     2   // store fn (bf16) for the scores pass
#define FL_OUT    4   // out += fn
#define FL_NEXT   8   // write ego_next / te_next
#define FL_FIN    16  // out = (out + fn) / 3
#define FL_ACONST 32  // scores: A_old == 1
#define FL_ASTORE 64  // scores: store A_new

static inline int ceil_div(int a, int b) { return (a + b - 1) / b; }

static __device__ inline float bf2f(unsigned short u) {
    return __uint_as_float(((unsigned int)u) << 16);
}
static __device__ inline float blo(unsigned int u) {   // low bf16 of packed pair
    return __uint_as_float(u << 16);
}
static __device__ inline float bhi(unsigned int u) {   // high bf16 of packed pair
    return __uint_as_float(u & 0xffff0000u);
}
static __device__ inline unsigned short f2bf(float f) {
    unsigned int x = __float_as_uint(f);
    x += 0x7fffu + ((x >> 16) & 1u);
    return (unsigned short)(x >> 16);
}

// ego = concat(user,item) bf16; te = tanh(l2norm chunk16) bf16; out = ego f32.
__global__ void k_init(const float* __restrict__ eu, const float* __restrict__ ei,
                       unsigned short* __restrict__ ego, unsigned short* __restrict__ te,
                       float* __restrict__ out) {
    int i = blockIdx.x * 256 + threadIdx.x;
    if (i >= NN * DIM_) return;
    float v = (i < NUSER * DIM_) ? eu[i] : ei[i - NUSER * DIM_];
    out[i] = v;
    ego[i] = f2bf(v);
    float s = v * v;
    s += __shfl_xor(s, 1); s += __shfl_xor(s, 2);
    s += __shfl_xor(s, 4); s += __shfl_xor(s, 8);
    float nrm = v / fmaxf(sqrtf(s), 1e-12f);
    float ex = __expf(2.0f * nrm);
    te[i] = f2bf((ex - 1.0f) / (ex + 1.0f));
}

// ---- CSR build (once per launch) ----
__global__ void k_hist(const int* __restrict__ head, int* __restrict__ deg) {
    int e = blockIdx.x * 256 + threadIdx.x;
    if (e < NNZ_) atomicAdd(&deg[head[e]], 1);
}

__global__ void k_blksum(const int* __restrict__ deg, int* __restrict__ partials) {
    __shared__ int sh[256];
    int i = blockIdx.x * 256 + threadIdx.x;
    sh[threadIdx.x] = (i < NN) ? deg[i] : 0;
    __syncthreads();
    for (int off = 128; off > 0; off >>= 1) {
        if (threadIdx.x < off) sh[threadIdx.x] += sh[threadIdx.x + off];
        __syncthreads();
    }
    if (threadIdx.x == 0) partials[blockIdx.x] = sh[0];
}

__global__ void k_scanp(const int* __restrict__ partials, int* __restrict__ blk_off,
                        int* __restrict__ row_start_end) {
    __shared__ int sh[512];
    int t = threadIdx.x;
    int v = (t < NBLK) ? partials[t] : 0;
    sh[t] = v;
    __syncthreads();
    for (int off = 1; off < 512; off <<= 1) {
        int u = 0;
        if (t >= off) u = sh[t - off];
        __syncthreads();
        sh[t] += u;
        __syncthreads();
    }
    if (t < NBLK) blk_off[t] = sh[t] - v;
    if (t == 511) row_start_end[0] = sh[511];
}

// row_start fill + d4_0 seed: rowsum_0 = 0.25*deg -> d4_0 = 2/sqrt(deg) (0 if deg=0).
__global__ void k_fill(const int* __restrict__ deg, const int* __restrict__ blk_off,
                       int* __restrict__ row_start, float4* __restrict__ d4a) {
    __shared__ int sh[256];
    int i = blockIdx.x * 256 + threadIdx.x;
    int v = (i < NN) ? deg[i] : 0;
    sh[threadIdx.x] = v;
    __syncthreads();
    for (int off = 1; off < 256; off <<= 1) {
        int u = 0;
        if (threadIdx.x >= off) u = sh[threadIdx.x - off];
        __syncthreads();
        sh[threadIdx.x] += u;
        __syncthreads();
    }
    if (i < NN) {
        row_start[i] = blk_off[blockIdx.x] + sh[threadIdx.x] - v;
        float dd = (v > 0) ? 2.0f / sqrtf((float)v) : 0.0f;
        d4a[i] = make_float4(dd, dd, dd, dd);
    }
}

__global__ void k_csrfill(const int* __restrict__ head, const int* __restrict__ tail,
                          const int* __restrict__ row_start, int* __restrict__ cursor,
                          int* __restrict__ csr_tail, int* __restrict__ csr_head) {
    int e = blockIdx.x * 256 + threadIdx.x;
    if (e >= NNZ_) return;
    int h = head[e];
    int pos = row_start[h] + atomicAdd(&cursor[h], 1);
    csr_tail[pos] = tail[e];
    csr_head[pos] = h;
}

// ---- walk1: one wave per node; fn = l2norm-chunk16 of the weighted gather ----
template<int FLAGS>
__global__ void k_iter(const unsigned short* __restrict__ svals,  // bf16 [NNZ*4]
                       const float* __restrict__ d4c,             // f32 [NN*4]
                       const unsigned short* __restrict__ ego,    // bf16 [NN*64]
                       const int* __restrict__ row_start, const int* __restrict__ csr_tail,
                       float* __restrict__ out,
                       unsigned short* __restrict__ fnb,          // bf16 [NN*64]
                       unsigned short* __restrict__ egon, unsigned short* __restrict__ ten) {
    int n = (blockIdx.x * 256 + threadIdx.x) >> 6;
    if (n >= NN) return;
    int j = threadIdx.x & 63;
    int f = j >> 4;
    int r0 = __builtin_amdgcn_readfirstlane(row_start[n]);
    int r1 = __builtin_amdgcn_readfirstlane(row_start[n + 1]);

    float acc = 0.0f;
    int k = r0;
    for (; k + 3 < r1; k += 4) {
        int t0 = csr_tail[k], t1 = csr_tail[k + 1], t2 = csr_tail[k + 2], t3 = csr_tail[k + 3];
        float w0, w1, w2, w3;
        if (FLAGS & FL_SVC) { w0 = w1 = w2 = w3 = 0.25f; }
        else {
            w0 = bf2f(svals[k * 4 + f]);       w1 = bf2f(svals[(k + 1) * 4 + f]);
            w2 = bf2f(svals[(k + 2) * 4 + f]); w3 = bf2f(svals[(k + 3) * 4 + f]);
        }
        w0 *= d4c[t0 * 4 + f]; w1 *= d4c[t1 * 4 + f];
        w2 *= d4c[t2 * 4 + f]; w3 *= d4c[t3 * 4 + f];
        acc += w0 * bf2f(ego[t0 * 64 + j]) + w1 * bf2f(ego[t1 * 64 + j])
             + w2 * bf2f(ego[t2 * 64 + j]) + w3 * bf2f(ego[t3 * 64 + j]);
    }
    for (; k < r1; ++k) {
        int t = csr_tail[k];
        float w = (FLAGS & FL_SVC) ? 0.25f : bf2f(svals[k * 4 + f]);
        acc += w * d4c[t * 4 + f] * bf2f(ego[t * 64 + j]);
    }

    float s = acc * acc;
    s += __shfl_xor(s, 1); s += __shfl_xor(s, 2);
    s += __shfl_xor(s, 4); s += __shfl_xor(s, 8);
    float fn = acc / fmaxf(sqrtf(s), 1e-12f);

    if (FLAGS & FL_FN)   fnb[n * 64 + j] = f2bf(fn);
    if (FLAGS & FL_FIN)      out[n * 64 + j] = (out[n * 64 + j] + fn) * (1.0f / 3.0f);
    else if (FLAGS & FL_OUT) out[n * 64 + j] += fn;
    if (FLAGS & FL_NEXT) {
        egon[n * 64 + j] = f2bf(fn);
        float ex = __expf(2.0f * fn);
        ten[n * 64 + j] = f2bf((ex - 1.0f) / (ex + 1.0f));
    }
}

// ---- scores + A-update + softmax, edge-parallel (no cross-lane ops) ----
template<int FLAGS>
__global__ void k_scores_edge(float4* __restrict__ A4,
                              const unsigned short* __restrict__ fnb,
                              const unsigned short* __restrict__ te,
                              const int* __restrict__ csr_head,
                              const int* __restrict__ csr_tail,
                              ushort4* __restrict__ svals) {
    int e = blockIdx.x * 256 + threadIdx.x;
    if (e >= NNZ_) return;
    int h = csr_head[e], t = csr_tail[e];
    const uint4* fh = (const uint4*)(fnb + (size_t)h * 64);
    const uint4* tv = (const uint4*)(te + (size_t)t * 64);
    float4 a = (FLAGS & FL_ACONST) ? make_float4(1.f, 1.f, 1.f, 1.f) : A4[e];
    float p[4];
#pragma unroll
    for (int f = 0; f < 4; ++f) {
        uint4 u0 = fh[f * 2], u1 = fh[f * 2 + 1];
        uint4 v0 = tv[f * 2], v1 = tv[f * 2 + 1];
        float s = blo(u0.x) * blo(v0.x) + bhi(u0.x) * bhi(v0.x)
                + blo(u0.y) * blo(v0.y) + bhi(u0.y) * bhi(v0.y)
                + blo(u0.z) * blo(v0.z) + bhi(u0.z) * bhi(v0.z)
                + blo(u0.w) * blo(v0.w) + bhi(u0.w) * bhi(v0.w)
                + blo(u1.x) * blo(v1.x) + bhi(u1.x) * bhi(v1.x)
                + blo(u1.y) * blo(v1.y) + bhi(u1.y) * bhi(v1.y)
                + blo(u1.z) * blo(v1.z) + bhi(u1.z) * bhi(v1.z)
                + blo(u1.w) * blo(v1.w) + bhi(u1.w) * bhi(v1.w);
        p[f] = s;
    }
    a.x += p[0]; a.y += p[1]; a.z += p[2]; a.w += p[3];
    if (FLAGS & FL_ASTORE) A4[e] = a;
    // softmax over factors, in-thread (A bounded in [-2,4]; exp safe in f32)
    float e0 = __expf(a.x), e1 = __expf(a.y), e2 = __expf(a.z), e3 = __expf(a.w);
    float inv = 1.0f / (e0 + e1 + e2 + e3);
    ushort4 o;
    o.x = f2bf(e0 * inv); o.y = f2bf(e1 * inv);
    o.z = f2bf(e2 * inv); o.w = f2bf(e3 * inv);
    svals[e] = o;
}

// rowsum of svals per node -> d4n (thread/node; neighbor threads read neighbor rows).
__global__ void k_dinv2(const ushort4* __restrict__ svals, const int* __restrict__ row_start,
                        float4* __restrict__ d4n) {
    int n = blockIdx.x * 256 + threadIdx.x;
    if (n >= NN) return;
    int r0 = row_start[n], r1 = row_start[n + 1];
    float s0 = 0.f, s1 = 0.f, s2 = 0.f, s3 = 0.f;
    for (int k = r0; k < r1; ++k) {
        ushort4 v = svals[k];
        s0 += bf2f(v.x); s1 += bf2f(v.y); s2 += bf2f(v.z); s3 += bf2f(v.w);
    }
    float4 d;
    d.x = (s0 > 0.f) ? 1.0f / sqrtf(fmaxf(s0, 1e-12f)) : 0.f;
    d.y = (s1 > 0.f) ? 1.0f / sqrtf(fmaxf(s1, 1e-12f)) : 0.f;
    d.z = (s2 > 0.f) ? 1.0f / sqrtf(fmaxf(s2, 1e-12f)) : 0.f;
    d.w = (s3 > 0.f) ? 1.0f / sqrtf(fmaxf(s3, 1e-12f)) : 0.f;
    d4n[n] = d;
}

extern "C" void kernel_launch(void* const* d_in, const int* in_sizes, int n_in,
                              void* d_out, int out_size, void* d_ws, size_t ws_size,
                              hipStream_t stream) {
    const float* eu = (const float*)d_in[0];
    const float* ei = (const float*)d_in[1];
    const int* head = (const int*)d_in[2];
    const int* tail = (const int*)d_in[3];
    float* out = (float*)d_out;   // 3-term accumulator, scaled at it3 (FL_FIN)

    // workspace layout — ~101 MB (16B-aligned first)
    float* A4 = (float*)d_ws;                               // 16 MB
    float* d4a = A4 + (size_t)NNZ_ * 4;                     // 1.6 MB
    float* d4b = d4a + (size_t)NN * 4;                      // 1.6 MB
    unsigned short* svals = (unsigned short*)(d4b + (size_t)NN * 4);  // 8 MB
    unsigned short* ego_a = svals + (size_t)NNZ_ * 4;       // 12.8 MB
    unsigned short* te_a  = ego_a + (size_t)NN * DIM_;      // 12.8 MB
    unsigned short* ego_b = te_a + (size_t)NN * DIM_;       // 12.8 MB
    unsigned short* te_b  = ego_b + (size_t)NN * DIM_;      // 12.8 MB
    unsigned short* fnb   = te_b + (size_t)NN * DIM_;       // 12.8 MB
    int* row_start = (int*)(fnb + (size_t)NN * DIM_);       // NN+1
    int* deg    = row_start + (NN + 1);                     // NN
    int* cursor = deg + NN;                                 // NN
    int* csr_tail = cursor + NN;                            // 4 MB
    int* csr_head = csr_tail + NNZ_;                        // 4 MB
    int* partials = csr_head + NNZ_;                        // NBLK
    int* blk_off  = partials + NBLK;                        // NBLK

    const int node_blocks = ceil_div(NN * DIM_, 256);      // 25000
    const int edge_blocks = ceil_div(NNZ_, 256);           // 3907
    const int wave_blocks = ceil_div(NN * 64, 256);        // 25000
    const int dinv_blocks = ceil_div(NN, 256);             // 391

    k_init<<<node_blocks, 256, 0, stream>>>(eu, ei, ego_a, te_a, out);

    // CSR build (graph constant within a launch) + d4_0 seed
    hipMemsetAsync(deg, 0, NN * sizeof(int), stream);
    k_hist<<<edge_blocks, 256, 0, stream>>>(head, deg);
    k_blksum<<<NBLK, 256, 0, stream>>>(deg, partials);
    k_scanp<<<1, 512, 0, stream>>>(partials, blk_off, &row_start[NN]);
    k_fill<<<NBLK, 256, 0, stream>>>(deg, blk_off, row_start, (float4*)d4a);
    hipMemsetAsync(cursor, 0, NN * sizeof(int), stream);
    k_csrfill<<<edge_blocks, 256, 0, stream>>>(head, tail, row_start, cursor,
                                               csr_tail, csr_head);

    // it0 = (0,0): walk1 with svals==0.25; fn -> fnb; scores A_old==1, store A_1.
    k_iter<FL_SVC | FL_FN><<<wave_blocks, 256, 0, stream>>>(
        svals, d4a, ego_a, row_start, csr_tail, out, fnb, ego_b, te_b);
    k_scores_edge<FL_ACONST | FL_ASTORE><<<edge_blocks, 256, 0, stream>>>(
        (float4*)A4, fnb, te_a, csr_head, csr_tail, (ushort4*)svals);
    k_dinv2<<<dinv_blocks, 256, 0, stream>>>((const ushort4*)svals, row_start, (float4*)d4b);

    // it1 = (0,1): layer-0 output; fn doubles as next ego (scores reads ego_b).
    k_iter<FL_OUT | FL_NEXT><<<wave_blocks, 256, 0, stream>>>(
        svals, d4b, ego_a, row_start, csr_tail, out, fnb, ego_b, te_b);
    k_scores_edge<FL_ASTORE><<<edge_blocks, 256, 0, stream>>>(
        (float4*)A4, ego_b, te_a, csr_head, csr_tail, (ushort4*)svals);
    k_dinv2<<<dinv_blocks, 256, 0, stream>>>((const ushort4*)svals, row_start, (float4*)d4a);

    // it2 = (1,0): fn -> fnb; scores store of A_3 dead (never read again).
    k_iter<FL_FN><<<wave_blocks, 256, 0, stream>>>(
        svals, d4a, ego_b, row_start, csr_tail, out, fnb, ego_a, te_a);
    k_scores_edge<0><<<edge_blocks, 256, 0, stream>>>(
        (float4*)A4, fnb, te_b, csr_head, csr_tail, (ushort4*)svals);
    k_dinv2<<<dinv_blocks, 256, 0, stream>>>((const ushort4*)svals, row_start, (float4*)d4b);

    // it3 = (1,1): no scores (dead); final out = (out + fn) / 3.
    k_iter<FL_OUT | FL_FIN><<<wave_blocks, 256, 0, stream>>>(
        svals, d4b, ego_b, row_start, csr_tail, out, fnb, ego_a, te_a);
}

// Round 10
// 480.354 us; speedup vs baseline: 5.3547x; 1.0788x over previous
//
#include <hip/hip_runtime.h>
#include <hip/hip_bf16.h>

// DGCF forward, MI355X. f32 in/out.
// R10: (1) csr_head filled node-parallel (coalesced) — csrfill scatters tail only,
// halving its write-line amplification; (2) walk1 restructured to 4 edges/wave-step
// (q=lane>>4 edge slot, l=lane&15 dim-quad; ego as ushort4/lane) -> ~4x fewer
// VMEM issues; cross-slot reduce once per row.
#define NUSER 50000
#define NITEM 50000
#define NN    100000          // NUSER+NITEM
#define NNZ_  1000000
#define DIM_  64
#define NBLK  391             // ceil_div(NN,256)

#define FL_SVC    1   // svals == 0.25 (iteration 0)
#define FL_FN     2   // store fn (bf16) for the scores pass
#define FL_OUT    4   // out += fn
#define FL_NEXT   8   // write ego_next / te_next
#define FL_FIN    16  // out = (out + fn) / 3
#define FL_ACONST 32  // scores: A_old == 1
#define FL_ASTORE 64  // scores: store A_new

static inline int ceil_div(int a, int b) { return (a + b - 1) / b; }

static __device__ inline float bf2f(unsigned short u) {
    return __uint_as_float(((unsigned int)u) << 16);
}
static __device__ inline float blo(unsigned int u) {
    return __uint_as_float(u << 16);
}
static __device__ inline float bhi(unsigned int u) {
    return __uint_as_float(u & 0xffff0000u);
}
static __device__ inline unsigned short f2bf(float f) {
    unsigned int x = __float_as_uint(f);
    x += 0x7fffu + ((x >> 16) & 1u);
    return (unsigned short)(x >> 16);
}

// ego = concat(user,item) bf16; te = tanh(l2norm chunk16) bf16; out = ego f32.
__global__ void k_init(const float* __restrict__ eu, const float* __restrict__ ei,
                       unsigned short* __restrict__ ego, unsigned short* __restrict__ te,
                       float* __restrict__ out) {
    int i = blockIdx.x * 256 + threadIdx.x;
    if (i >= NN * DIM_) return;
    float v = (i < NUSER * DIM_) ? eu[i] : ei[i - NUSER * DIM_];
    out[i] = v;
    ego[i] = f2bf(v);
    float s = v * v;
    s += __shfl_xor(s, 1); s += __shfl_xor(s, 2);
    s += __shfl_xor(s, 4); s += __shfl_xor(s, 8);
    float nrm = v / fmaxf(sqrtf(s), 1e-12f);
    float ex = __expf(2.0f * nrm);
    te[i] = f2bf((ex - 1.0f) / (ex + 1.0f));
}

// ---- CSR build (once per launch) ----
__global__ void k_hist(const int* __restrict__ head, int* __restrict__ deg) {
    int e = blockIdx.x * 256 + threadIdx.x;
    if (e < NNZ_) atomicAdd(&deg[head[e]], 1);
}

__global__ void k_blksum(const int* __restrict__ deg, int* __restrict__ partials) {
    __shared__ int sh[256];
    int i = blockIdx.x * 256 + threadIdx.x;
    sh[threadIdx.x] = (i < NN) ? deg[i] : 0;
    __syncthreads();
    for (int off = 128; off > 0; off >>= 1) {
        if (threadIdx.x < off) sh[threadIdx.x] += sh[threadIdx.x + off];
        __syncthreads();
    }
    if (threadIdx.x == 0) partials[blockIdx.x] = sh[0];
}

__global__ void k_scanp(const int* __restrict__ partials, int* __restrict__ blk_off,
                        int* __restrict__ row_start_end) {
    __shared__ int sh[512];
    int t = threadIdx.x;
    int v = (t < NBLK) ? partials[t] : 0;
    sh[t] = v;
    __syncthreads();
    for (int off = 1; off < 512; off <<= 1) {
        int u = 0;
        if (t >= off) u = sh[t - off];
        __syncthreads();
        sh[t] += u;
        __syncthreads();
    }
    if (t < NBLK) blk_off[t] = sh[t] - v;
    if (t == 511) row_start_end[0] = sh[511];
}

// row_start fill + d4_0 seed: rowsum_0 = 0.25*deg -> d4_0 = 2/sqrt(deg) (0 if deg=0).
__global__ void k_fill(const int* __restrict__ deg, const int* __restrict__ blk_off,
                       int* __restrict__ row_start, float4* __restrict__ d4a) {
    __shared__ int sh[256];
    int i = blockIdx.x * 256 + threadIdx.x;
    int v = (i < NN) ? deg[i] : 0;
    sh[threadIdx.x] = v;
    __syncthreads();
    for (int off = 1; off < 256; off <<= 1) {
        int u = 0;
        if (threadIdx.x >= off) u = sh[threadIdx.x - off];
        __syncthreads();
        sh[threadIdx.x] += u;
        __syncthreads();
    }
    if (i < NN) {
        row_start[i] = blk_off[blockIdx.x] + sh[threadIdx.x] - v;
        float dd = (v > 0) ? 2.0f / sqrtf((float)v) : 0.0f;
        d4a[i] = make_float4(dd, dd, dd, dd);
    }
}

// scatter tails only (head is filled coalesced by k_headfill)
__global__ void k_csrfill(const int* __restrict__ head, const int* __restrict__ tail,
                          const int* __restrict__ row_start, int* __restrict__ cursor,
                          int* __restrict__ csr_tail) {
    int e = blockIdx.x * 256 + threadIdx.x;
    if (e >= NNZ_) return;
    int h = head[e];
    int pos = row_start[h] + atomicAdd(&cursor[h], 1);
    csr_tail[pos] = tail[e];
}

// csr_head is piecewise-constant in CSR order: fill node-parallel, coalesced.
__global__ void k_headfill(const int* __restrict__ row_start, int* __restrict__ csr_head) {
    int n = blockIdx.x * 256 + threadIdx.x;
    if (n >= NN) return;
    int r0 = row_start[n], r1 = row_start[n + 1];
    for (int k = r0; k < r1; ++k) csr_head[k] = n;
}

// ---- walk1: one wave per node, 4 edges per step ----
// lane = 16*q + l: q = edge slot (0..3), l = dim quad (dims 4l..4l+3), f = l>>2.
// acc(dim quad) accumulated per slot; cross-slot shuffle reduce once per row.
template<int FLAGS>
__global__ void k_iter(const unsigned short* __restrict__ svals,  // bf16 [NNZ*4]
                       const float* __restrict__ d4c,             // f32 [NN*4]
                       const unsigned short* __restrict__ ego,    // bf16 [NN*64]
                       const int* __restrict__ row_start, const int* __restrict__ csr_tail,
                       float* __restrict__ out,
                       unsigned short* __restrict__ fnb,          // bf16 [NN*64]
                       unsigned short* __restrict__ egon, unsigned short* __restrict__ ten) {
    int n = (blockIdx.x * 256 + threadIdx.x) >> 6;
    if (n >= NN) return;
    int lane = threadIdx.x & 63;
    int q = lane >> 4;
    int l = lane & 15;
    int f = l >> 2;
    int r0 = __builtin_amdgcn_readfirstlane(row_start[n]);
    int r1 = __builtin_amdgcn_readfirstlane(row_start[n + 1]);

    float ax = 0.f, ay = 0.f, az = 0.f, aw = 0.f;
    int kb = r0;
    // unroll 2 (8 edges in flight)
    for (; kb + 7 < r1; kb += 8) {
        int i0 = kb + q, i1 = kb + 4 + q;
        int t0 = csr_tail[i0], t1 = csr_tail[i1];
        float w0, w1;
        if (FLAGS & FL_SVC) { w0 = 0.25f; w1 = 0.25f; }
        else { w0 = bf2f(svals[i0 * 4 + f]); w1 = bf2f(svals[i1 * 4 + f]); }
        w0 *= d4c[t0 * 4 + f]; w1 *= d4c[t1 * 4 + f];
        ushort4 u0 = *(const ushort4*)(ego + (size_t)t0 * 64 + 4 * l);
        ushort4 u1 = *(const ushort4*)(ego + (size_t)t1 * 64 + 4 * l);
        ax += w0 * bf2f(u0.x) + w1 * bf2f(u1.x);
        ay += w0 * bf2f(u0.y) + w1 * bf2f(u1.y);
        az += w0 * bf2f(u0.z) + w1 * bf2f(u1.z);
        aw += w0 * bf2f(u0.w) + w1 * bf2f(u1.w);
    }
    // remainder (<=7 edges), predicated 4-wide
    for (; kb < r1; kb += 4) {
        int i0 = kb + q;
        bool v = (i0 < r1);
        int ic = v ? i0 : r0;
        int t0 = csr_tail[ic];
        float w0 = (FLAGS & FL_SVC) ? 0.25f : bf2f(svals[ic * 4 + f]);
        w0 *= d4c[t0 * 4 + f];
        w0 = v ? w0 : 0.0f;
        ushort4 u0 = *(const ushort4*)(ego + (size_t)t0 * 64 + 4 * l);
        ax += w0 * bf2f(u0.x); ay += w0 * bf2f(u0.y);
        az += w0 * bf2f(u0.z); aw += w0 * bf2f(u0.w);
    }

    // cross-edge-slot reduce (once per row)
    ax += __shfl_xor(ax, 16); ax += __shfl_xor(ax, 32);
    ay += __shfl_xor(ay, 16); ay += __shfl_xor(ay, 32);
    az += __shfl_xor(az, 16); az += __shfl_xor(az, 32);
    aw += __shfl_xor(aw, 16); aw += __shfl_xor(aw, 32);
    // chunk-16 l2 norm: lane covers 4 dims; chunk = 4-lane group (xor 1,2 on l)
    float s = ax * ax + ay * ay + az * az + aw * aw;
    s += __shfl_xor(s, 1); s += __shfl_xor(s, 2);
    float inv = 1.0f / fmaxf(sqrtf(s), 1e-12f);
    float fx = ax * inv, fy = ay * inv, fz = az * inv, fw = aw * inv;

    if (q == 0) {
        if (FLAGS & FL_FN) {
            ushort4 o; o.x = f2bf(fx); o.y = f2bf(fy); o.z = f2bf(fz); o.w = f2bf(fw);
            *(ushort4*)(fnb + (size_t)n * 64 + 4 * l) = o;
        }
        if (FLAGS & FL_FIN) {
            float4* po = (float4*)(out + (size_t)n * 64 + 4 * l);
            float4 ov = *po;
            ov.x = (ov.x + fx) * (1.0f / 3.0f); ov.y = (ov.y + fy) * (1.0f / 3.0f);
            ov.z = (ov.z + fz) * (1.0f / 3.0f); ov.w = (ov.w + fw) * (1.0f / 3.0f);
            *po = ov;
        } else if (FLAGS & FL_OUT) {
            float4* po = (float4*)(out + (size_t)n * 64 + 4 * l);
            float4 ov = *po;
            ov.x += fx; ov.y += fy; ov.z += fz; ov.w += fw;
            *po = ov;
        }
        if (FLAGS & FL_NEXT) {
            ushort4 o; o.x = f2bf(fx); o.y = f2bf(fy); o.z = f2bf(fz); o.w = f2bf(fw);
            *(ushort4*)(egon + (size_t)n * 64 + 4 * l) = o;
            float e0 = __expf(2.0f * fx), e1 = __expf(2.0f * fy);
            float e2 = __expf(2.0f * fz), e3 = __expf(2.0f * fw);
            ushort4 p;
            p.x = f2bf((e0 - 1.0f) / (e0 + 1.0f)); p.y = f2bf((e1 - 1.0f) / (e1 + 1.0f));
            p.z = f2bf((e2 - 1.0f) / (e2 + 1.0f)); p.w = f2bf((e3 - 1.0f) / (e3 + 1.0f));
            *(ushort4*)(ten + (size_t)n * 64 + 4 * l) = p;
        }
    }
}

// ---- scores + A-update + softmax, edge-parallel (no cross-lane ops) ----
template<int FLAGS>
__global__ void k_scores_edge(float4* __restrict__ A4,
                              const unsigned short* __restrict__ fnb,
                              const unsigned short* __restrict__ te,
                              const int* __restrict__ csr_head,
                              const int* __restrict__ csr_tail,
                              ushort4* __restrict__ svals) {
    int e = blockIdx.x * 256 + threadIdx.x;
    if (e >= NNZ_) return;
    int h = csr_head[e], t = csr_tail[e];
    const uint4* fh = (const uint4*)(fnb + (size_t)h * 64);
    const uint4* tv = (const uint4*)(te + (size_t)t * 64);
    float4 a = (FLAGS & FL_ACONST) ? make_float4(1.f, 1.f, 1.f, 1.f) : A4[e];
    float p[4];
#pragma unroll
    for (int f = 0; f < 4; ++f) {
        uint4 u0 = fh[f * 2], u1 = fh[f * 2 + 1];
        uint4 v0 = tv[f * 2], v1 = tv[f * 2 + 1];
        float s = blo(u0.x) * blo(v0.x) + bhi(u0.x) * bhi(v0.x)
                + blo(u0.y) * blo(v0.y) + bhi(u0.y) * bhi(v0.y)
                + blo(u0.z) * blo(v0.z) + bhi(u0.z) * bhi(v0.z)
                + blo(u0.w) * blo(v0.w) + bhi(u0.w) * bhi(v0.w)
                + blo(u1.x) * blo(v1.x) + bhi(u1.x) * bhi(v1.x)
                + blo(u1.y) * blo(v1.y) + bhi(u1.y) * bhi(v1.y)
                + blo(u1.z) * blo(v1.z) + bhi(u1.z) * bhi(v1.z)
                + blo(u1.w) * blo(v1.w) + bhi(u1.w) * bhi(v1.w);
        p[f] = s;
    }
    a.x += p[0]; a.y += p[1]; a.z += p[2]; a.w += p[3];
    if (FLAGS & FL_ASTORE) A4[e] = a;
    float e0 = __expf(a.x), e1 = __expf(a.y), e2 = __expf(a.z), e3 = __expf(a.w);
    float inv = 1.0f / (e0 + e1 + e2 + e3);
    ushort4 o;
    o.x = f2bf(e0 * inv); o.y = f2bf(e1 * inv);
    o.z = f2bf(e2 * inv); o.w = f2bf(e3 * inv);
    svals[e] = o;
}

// rowsum of svals per node -> d4n (thread/node).
__global__ void k_dinv2(const ushort4* __restrict__ svals, const int* __restrict__ row_start,
                        float4* __restrict__ d4n) {
    int n = blockIdx.x * 256 + threadIdx.x;
    if (n >= NN) return;
    int r0 = row_start[n], r1 = row_start[n + 1];
    float s0 = 0.f, s1 = 0.f, s2 = 0.f, s3 = 0.f;
    for (int k = r0; k < r1; ++k) {
        ushort4 v = svals[k];
        s0 += bf2f(v.x); s1 += bf2f(v.y); s2 += bf2f(v.z); s3 += bf2f(v.w);
    }
    float4 d;
    d.x = (s0 > 0.f) ? 1.0f / sqrtf(fmaxf(s0, 1e-12f)) : 0.f;
    d.y = (s1 > 0.f) ? 1.0f / sqrtf(fmaxf(s1, 1e-12f)) : 0.f;
    d.z = (s2 > 0.f) ? 1.0f / sqrtf(fmaxf(s2, 1e-12f)) : 0.f;
    d.w = (s3 > 0.f) ? 1.0f / sqrtf(fmaxf(s3, 1e-12f)) : 0.f;
    d4n[n] = d;
}

extern "C" void kernel_launch(void* const* d_in, const int* in_sizes, int n_in,
                              void* d_out, int out_size, void* d_ws, size_t ws_size,
                              hipStream_t stream) {
    const float* eu = (const float*)d_in[0];
    const float* ei = (const float*)d_in[1];
    const int* head = (const int*)d_in[2];
    const int* tail = (const int*)d_in[3];
    float* out = (float*)d_out;   // 3-term accumulator, scaled at it3 (FL_FIN)

    // workspace layout — ~101 MB (16B-aligned first)
    float* A4 = (float*)d_ws;                               // 16 MB
    float* d4a = A4 + (size_t)NNZ_ * 4;                     // 1.6 MB
    float* d4b = d4a + (size_t)NN * 4;                      // 1.6 MB
    unsigned short* svals = (unsigned short*)(d4b + (size_t)NN * 4);  // 8 MB
    unsigned short* ego_a = svals + (size_t)NNZ_ * 4;       // 12.8 MB
    unsigned short* te_a  = ego_a + (size_t)NN * DIM_;      // 12.8 MB
    unsigned short* ego_b = te_a + (size_t)NN * DIM_;       // 12.8 MB
    unsigned short* te_b  = ego_b + (size_t)NN * DIM_;      // 12.8 MB
    unsigned short* fnb   = te_b + (size_t)NN * DIM_;       // 12.8 MB
    int* row_start = (int*)(fnb + (size_t)NN * DIM_);       // NN+1
    int* deg    = row_start + (NN + 1);                     // NN
    int* cursor = deg + NN;                                 // NN
    int* csr_tail = cursor + NN;                            // 4 MB
    int* csr_head = csr_tail + NNZ_;                        // 4 MB
    int* partials = csr_head + NNZ_;                        // NBLK
    int* blk_off  = partials + NBLK;                        // NBLK

    const int node_blocks = ceil_div(NN * DIM_, 256);      // 25000
    const int edge_blocks = ceil_div(NNZ_, 256);           // 3907
    const int wave_blocks = ceil_div(NN * 64, 256);        // 25000
    const int dinv_blocks = ceil_div(NN, 256);             // 391

    k_init<<<node_blocks, 256, 0, stream>>>(eu, ei, ego_a, te_a, out);

    // CSR build (graph constant within a launch) + d4_0 seed
    hipMemsetAsync(deg, 0, NN * sizeof(int), stream);
    k_hist<<<edge_blocks, 256, 0, stream>>>(head, deg);
    k_blksum<<<NBLK, 256, 0, stream>>>(deg, partials);
    k_scanp<<<1, 512, 0, stream>>>(partials, blk_off, &row_start[NN]);
    k_fill<<<NBLK, 256, 0, stream>>>(deg, blk_off, row_start, (float4*)d4a);
    hipMemsetAsync(cursor, 0, NN * sizeof(int), stream);
    k_csrfill<<<edge_blocks, 256, 0, stream>>>(head, tail, row_start, cursor, csr_tail);
    k_headfill<<<dinv_blocks, 256, 0, stream>>>(row_start, csr_head);

    // it0 = (0,0): walk1 with svals==0.25; fn -> fnb; scores A_old==1, store A_1.
    k_iter<FL_SVC | FL_FN><<<wave_blocks, 256, 0, stream>>>(
        svals, d4a, ego_a, row_start, csr_tail, out, fnb, ego_b, te_b);
    k_scores_edge<FL_ACONST | FL_ASTORE><<<edge_blocks, 256, 0, stream>>>(
        (float4*)A4, fnb, te_a, csr_head, csr_tail, (ushort4*)svals);
    k_dinv2<<<dinv_blocks, 256, 0, stream>>>((const ushort4*)svals, row_start, (float4*)d4b);

    // it1 = (0,1): layer-0 output; fn doubles as next ego (scores reads ego_b).
    k_iter<FL_OUT | FL_NEXT><<<wave_blocks, 256, 0, stream>>>(
        svals, d4b, ego_a, row_start, csr_tail, out, fnb, ego_b, te_b);
    k_scores_edge<FL_ASTORE><<<edge_blocks, 256, 0, stream>>>(
        (float4*)A4, ego_b, te_a, csr_head, csr_tail, (ushort4*)svals);
    k_dinv2<<<dinv_blocks, 256, 0, stream>>>((const ushort4*)svals, row_start, (float4*)d4a);

    // it2 = (1,0): fn -> fnb; scores store of A_3 dead (never read again).
    k_iter<FL_FN><<<wave_blocks, 256, 0, stream>>>(
        svals, d4a, ego_b, row_start, csr_tail, out, fnb, ego_a, te_a);
    k_scores_edge<0><<<edge_blocks, 256, 0, stream>>>(
        (float4*)A4, fnb, te_b, csr_head, csr_tail, (ushort4*)svals);
    k_dinv2<<<dinv_blocks, 256, 0, stream>>>((const ushort4*)svals, row_start, (float4*)d4b);

    // it3 = (1,1): no scores (dead); final out = (out + fn) / 3.
    k_iter<FL_OUT | FL_FIN><<<wave_blocks, 256, 0, stream>>>(
        svals, d4b, ego_b, row_start, csr_tail, out, fnb, ego_a, te_a);
}

// Round 11
// 420.512 us; speedup vs baseline: 6.1167x; 1.1423x over previous
//
#include <hip/hip_runtime.h>
#include <hip/hip_bf16.h>

// DGCF forward, MI355X. f32 in/out.
// R11: bucketed CSR build. bucket = head>>8 (391 buckets x 256 nodes).
// count (LDS hist) -> scan -> bin-scatter (chunk-reserved, int2 pairs) ->
// per-bucket CSR (LDS deg/scan/cursor; scatter confined to 10 KB L2-hot window).
// Replaces hist/blksum/scanp/fill/csrfill (~115us of cross-XCD atomic scatter).
#define NUSER 50000
#define NITEM 50000
#define NN    100000          // NUSER+NITEM
#define NNZ_  1000000
#define DIM_  64
#define NBLK  391             // ceil_div(NN,256) == bucket count
#define EPB   2560            // edges per bin-pass block (391*2560 >= NNZ)

#define FL_SVC    1   // svals == 0.25 (iteration 0)
#define FL_FN     2   // store fn (bf16) for the scores pass
#define FL_OUT    4   // out += fn
#define FL_NEXT   8   // write ego_next / te_next
#define FL_FIN    16  // out = (out + fn) / 3
#define FL_ACONST 32  // scores: A_old == 1
#define FL_ASTORE 64  // scores: store A_new

static inline int ceil_div(int a, int b) { return (a + b - 1) / b; }

static __device__ inline float bf2f(unsigned short u) {
    return __uint_as_float(((unsigned int)u) << 16);
}
static __device__ inline float blo(unsigned int u) {
    return __uint_as_float(u << 16);
}
static __device__ inline float bhi(unsigned int u) {
    return __uint_as_float(u & 0xffff0000u);
}
static __device__ inline unsigned short f2bf(float f) {
    unsigned int x = __float_as_uint(f);
    x += 0x7fffu + ((x >> 16) & 1u);
    return (unsigned short)(x >> 16);
}

// ego = concat(user,item) bf16; te = tanh(l2norm chunk16) bf16; out = ego f32.
__global__ void k_init(const float* __restrict__ eu, const float* __restrict__ ei,
                       unsigned short* __restrict__ ego, unsigned short* __restrict__ te,
                       float* __restrict__ out) {
    int i = blockIdx.x * 256 + threadIdx.x;
    if (i >= NN * DIM_) return;
    float v = (i < NUSER * DIM_) ? eu[i] : ei[i - NUSER * DIM_];
    out[i] = v;
    ego[i] = f2bf(v);
    float s = v * v;
    s += __shfl_xor(s, 1); s += __shfl_xor(s, 2);
    s += __shfl_xor(s, 4); s += __shfl_xor(s, 8);
    float nrm = v / fmaxf(sqrtf(s), 1e-12f);
    float ex = __expf(2.0f * nrm);
    te[i] = f2bf((ex - 1.0f) / (ex + 1.0f));
}

// ---- bucketed CSR build (once per launch) ----
// 1) per-bucket edge counts (LDS hist, one global atomic per block x bucket)
__global__ void k_bcount(const int* __restrict__ head, int* __restrict__ bcount) {
    __shared__ int cnt[NBLK];
    int tid = threadIdx.x;
    for (int i = tid; i < NBLK; i += 256) cnt[i] = 0;
    __syncthreads();
    int e0 = blockIdx.x * EPB;
    int e1 = min(e0 + EPB, NNZ_);
    for (int e = e0 + tid; e < e1; e += 256)
        atomicAdd(&cnt[head[e] >> 8], 1);
    __syncthreads();
    for (int i = tid; i < NBLK; i += 256)
        if (cnt[i]) atomicAdd(&bcount[i], cnt[i]);
}

// 2) exclusive scan of bucket counts -> bucket_base (shared by bin & csr regions);
//    init bucket_cursor; row_start[NN] = NNZ.
__global__ void k_bscan(const int* __restrict__ bcount, int* __restrict__ bucket_base,
                        int* __restrict__ bucket_cursor, int* __restrict__ row_start_end) {
    __shared__ int sh[512];
    int t = threadIdx.x;
    int v = (t < NBLK) ? bcount[t] : 0;
    sh[t] = v;
    __syncthreads();
    for (int off = 1; off < 512; off <<= 1) {
        int u = 0;
        if (t >= off) u = sh[t - off];
        __syncthreads();
        sh[t] += u;
        __syncthreads();
    }
    if (t < NBLK) {
        int base = sh[t] - v;
        bucket_base[t] = base;
        bucket_cursor[t] = base;
    }
    if (t == 511) {
        bucket_base[NBLK] = sh[511];    // == NNZ_
        row_start_end[0] = sh[511];
    }
}

// 3) scatter (head,tail) pairs into per-bucket bin regions (chunk reservation)
__global__ void k_binscat(const int* __restrict__ head, const int* __restrict__ tail,
                          int* __restrict__ bucket_cursor, int2* __restrict__ bin) {
    __shared__ int cnt[NBLK];
    __shared__ int chunk[NBLK];
    int tid = threadIdx.x;
    for (int i = tid; i < NBLK; i += 256) cnt[i] = 0;
    __syncthreads();
    int e0 = blockIdx.x * EPB;
    int e1 = min(e0 + EPB, NNZ_);
    for (int e = e0 + tid; e < e1; e += 256)
        atomicAdd(&cnt[head[e] >> 8], 1);
    __syncthreads();
    for (int i = tid; i < NBLK; i += 256) {
        chunk[i] = cnt[i] ? atomicAdd(&bucket_cursor[i], cnt[i]) : 0;
        cnt[i] = 0;   // reuse as local cursor
    }
    __syncthreads();
    for (int e = e0 + tid; e < e1; e += 256) {
        int h = head[e], t = tail[e];
        int b = h >> 8;
        int off = atomicAdd(&cnt[b], 1);
        bin[chunk[b] + off] = make_int2(h, t);
    }
}

// 4) per-bucket CSR: LDS deg hist -> scan -> row_start + d4a seed (coalesced);
//    tail scatter via LDS cursors into the bucket's contiguous csr window.
__global__ void k_bucket(const int2* __restrict__ bin, const int* __restrict__ bucket_base,
                         int* __restrict__ row_start, float4* __restrict__ d4a,
                         int* __restrict__ csr_tail) {
    __shared__ int deg[256];
    __shared__ int sh[256];
    __shared__ int cur[256];
    int tid = threadIdx.x;
    int b = blockIdx.x;
    int n0 = b << 8;
    int e0 = bucket_base[b], e1 = bucket_base[b + 1];
    deg[tid] = 0;
    __syncthreads();
    for (int e = e0 + tid; e < e1; e += 256)
        atomicAdd(&deg[bin[e].x - n0], 1);
    __syncthreads();
    int myDeg = deg[tid];
    sh[tid] = myDeg;
    __syncthreads();
    for (int off = 1; off < 256; off <<= 1) {
        int u = 0;
        if (tid >= off) u = sh[tid - off];
        __syncthreads();
        sh[tid] += u;
        __syncthreads();
    }
    int loff = sh[tid] - myDeg;   // exclusive local offset
    int n = n0 + tid;
    if (n < NN) {
        row_start[n] = e0 + loff;
        float dd = (myDeg > 0) ? 2.0f / sqrtf((float)myDeg) : 0.0f;
        d4a[n] = make_float4(dd, dd, dd, dd);
    }
    cur[tid] = e0 + loff;
    __syncthreads();
    for (int e = e0 + tid; e < e1; e += 256) {
        int2 p = bin[e];
        int pos = atomicAdd(&cur[p.x - n0], 1);
        csr_tail[pos] = p.y;
    }
}

// csr_head is piecewise-constant in CSR order: fill node-parallel, coalesced.
__global__ void k_headfill(const int* __restrict__ row_start, int* __restrict__ csr_head) {
    int n = blockIdx.x * 256 + threadIdx.x;
    if (n >= NN) return;
    int r0 = row_start[n], r1 = row_start[n + 1];
    for (int k = r0; k < r1; ++k) csr_head[k] = n;
}

// ---- walk1: one wave per node, 4 edges per step ----
// lane = 16*q + l: q = edge slot (0..3), l = dim quad (dims 4l..4l+3), f = l>>2.
template<int FLAGS>
__global__ void k_iter(const unsigned short* __restrict__ svals,  // bf16 [NNZ*4]
                       const float* __restrict__ d4c,             // f32 [NN*4]
                       const unsigned short* __restrict__ ego,    // bf16 [NN*64]
                       const int* __restrict__ row_start, const int* __restrict__ csr_tail,
                       float* __restrict__ out,
                       unsigned short* __restrict__ fnb,          // bf16 [NN*64]
                       unsigned short* __restrict__ egon, unsigned short* __restrict__ ten) {
    int n = (blockIdx.x * 256 + threadIdx.x) >> 6;
    if (n >= NN) return;
    int lane = threadIdx.x & 63;
    int q = lane >> 4;
    int l = lane & 15;
    int f = l >> 2;
    int r0 = __builtin_amdgcn_readfirstlane(row_start[n]);
    int r1 = __builtin_amdgcn_readfirstlane(row_start[n + 1]);

    float ax = 0.f, ay = 0.f, az = 0.f, aw = 0.f;
    int kb = r0;
    for (; kb + 7 < r1; kb += 8) {
        int i0 = kb + q, i1 = kb + 4 + q;
        int t0 = csr_tail[i0], t1 = csr_tail[i1];
        float w0, w1;
        if (FLAGS & FL_SVC) { w0 = 0.25f; w1 = 0.25f; }
        else { w0 = bf2f(svals[i0 * 4 + f]); w1 = bf2f(svals[i1 * 4 + f]); }
        w0 *= d4c[t0 * 4 + f]; w1 *= d4c[t1 * 4 + f];
        ushort4 u0 = *(const ushort4*)(ego + (size_t)t0 * 64 + 4 * l);
        ushort4 u1 = *(const ushort4*)(ego + (size_t)t1 * 64 + 4 * l);
        ax += w0 * bf2f(u0.x) + w1 * bf2f(u1.x);
        ay += w0 * bf2f(u0.y) + w1 * bf2f(u1.y);
        az += w0 * bf2f(u0.z) + w1 * bf2f(u1.z);
        aw += w0 * bf2f(u0.w) + w1 * bf2f(u1.w);
    }
    for (; kb < r1; kb += 4) {
        int i0 = kb + q;
        bool v = (i0 < r1);
        int ic = v ? i0 : r0;
        int t0 = csr_tail[ic];
        float w0 = (FLAGS & FL_SVC) ? 0.25f : bf2f(svals[ic * 4 + f]);
        w0 *= d4c[t0 * 4 + f];
        w0 = v ? w0 : 0.0f;
        ushort4 u0 = *(const ushort4*)(ego + (size_t)t0 * 64 + 4 * l);
        ax += w0 * bf2f(u0.x); ay += w0 * bf2f(u0.y);
        az += w0 * bf2f(u0.z); aw += w0 * bf2f(u0.w);
    }

    ax += __shfl_xor(ax, 16); ax += __shfl_xor(ax, 32);
    ay += __shfl_xor(ay, 16); ay += __shfl_xor(ay, 32);
    az += __shfl_xor(az, 16); az += __shfl_xor(az, 32);
    aw += __shfl_xor(aw, 16); aw += __shfl_xor(aw, 32);
    float s = ax * ax + ay * ay + az * az + aw * aw;
    s += __shfl_xor(s, 1); s += __shfl_xor(s, 2);
    float inv = 1.0f / fmaxf(sqrtf(s), 1e-12f);
    float fx = ax * inv, fy = ay * inv, fz = az * inv, fw = aw * inv;

    if (q == 0) {
        if (FLAGS & FL_FN) {
            ushort4 o; o.x = f2bf(fx); o.y = f2bf(fy); o.z = f2bf(fz); o.w = f2bf(fw);
            *(ushort4*)(fnb + (size_t)n * 64 + 4 * l) = o;
        }
        if (FLAGS & FL_FIN) {
            float4* po = (float4*)(out + (size_t)n * 64 + 4 * l);
            float4 ov = *po;
            ov.x = (ov.x + fx) * (1.0f / 3.0f); ov.y = (ov.y + fy) * (1.0f / 3.0f);
            ov.z = (ov.z + fz) * (1.0f / 3.0f); ov.w = (ov.w + fw) * (1.0f / 3.0f);
            *po = ov;
        } else if (FLAGS & FL_OUT) {
            float4* po = (float4*)(out + (size_t)n * 64 + 4 * l);
            float4 ov = *po;
            ov.x += fx; ov.y += fy; ov.z += fz; ov.w += fw;
            *po = ov;
        }
        if (FLAGS & FL_NEXT) {
            ushort4 o; o.x = f2bf(fx); o.y = f2bf(fy); o.z = f2bf(fz); o.w = f2bf(fw);
            *(ushort4*)(egon + (size_t)n * 64 + 4 * l) = o;
            float e0 = __expf(2.0f * fx), e1 = __expf(2.0f * fy);
            float e2 = __expf(2.0f * fz), e3 = __expf(2.0f * fw);
            ushort4 p;
            p.x = f2bf((e0 - 1.0f) / (e0 + 1.0f)); p.y = f2bf((e1 - 1.0f) / (e1 + 1.0f));
            p.z = f2bf((e2 - 1.0f) / (e2 + 1.0f)); p.w = f2bf((e3 - 1.0f) / (e3 + 1.0f));
            *(ushort4*)(ten + (size_t)n * 64 + 4 * l) = p;
        }
    }
}

// ---- scores + A-update + softmax, edge-parallel (no cross-lane ops) ----
template<int FLAGS>
__global__ void k_scores_edge(float4* __restrict__ A4,
                              const unsigned short* __restrict__ fnb,
                              const unsigned short* __restrict__ te,
                              const int* __restrict__ csr_head,
                              const int* __restrict__ csr_tail,
                              ushort4* __restrict__ svals) {
    int e = blockIdx.x * 256 + threadIdx.x;
    if (e >= NNZ_) return;
    int h = csr_head[e], t = csr_tail[e];
    const uint4* fh = (const uint4*)(fnb + (size_t)h * 64);
    const uint4* tv = (const uint4*)(te + (size_t)t * 64);
    float4 a = (FLAGS & FL_ACONST) ? make_float4(1.f, 1.f, 1.f, 1.f) : A4[e];
    float p[4];
#pragma unroll
    for (int f = 0; f < 4; ++f) {
        uint4 u0 = fh[f * 2], u1 = fh[f * 2 + 1];
        uint4 v0 = tv[f * 2], v1 = tv[f * 2 + 1];
        float s = blo(u0.x) * blo(v0.x) + bhi(u0.x) * bhi(v0.x)
                + blo(u0.y) * blo(v0.y) + bhi(u0.y) * bhi(v0.y)
                + blo(u0.z) * blo(v0.z) + bhi(u0.z) * bhi(v0.z)
                + blo(u0.w) * blo(v0.w) + bhi(u0.w) * bhi(v0.w)
                + blo(u1.x) * blo(v1.x) + bhi(u1.x) * bhi(v1.x)
                + blo(u1.y) * blo(v1.y) + bhi(u1.y) * bhi(v1.y)
                + blo(u1.z) * blo(v1.z) + bhi(u1.z) * bhi(v1.z)
                + blo(u1.w) * blo(v1.w) + bhi(u1.w) * bhi(v1.w);
        p[f] = s;
    }
    a.x += p[0]; a.y += p[1]; a.z += p[2]; a.w += p[3];
    if (FLAGS & FL_ASTORE) A4[e] = a;
    float e0 = __expf(a.x), e1 = __expf(a.y), e2 = __expf(a.z), e3 = __expf(a.w);
    float inv = 1.0f / (e0 + e1 + e2 + e3);
    ushort4 o;
    o.x = f2bf(e0 * inv); o.y = f2bf(e1 * inv);
    o.z = f2bf(e2 * inv); o.w = f2bf(e3 * inv);
    svals[e] = o;
}

// rowsum of svals per node -> d4n (thread/node).
__global__ void k_dinv2(const ushort4* __restrict__ svals, const int* __restrict__ row_start,
                        float4* __restrict__ d4n) {
    int n = blockIdx.x * 256 + threadIdx.x;
    if (n >= NN) return;
    int r0 = row_start[n], r1 = row_start[n + 1];
    float s0 = 0.f, s1 = 0.f, s2 = 0.f, s3 = 0.f;
    for (int k = r0; k < r1; ++k) {
        ushort4 v = svals[k];
        s0 += bf2f(v.x); s1 += bf2f(v.y); s2 += bf2f(v.z); s3 += bf2f(v.w);
    }
    float4 d;
    d.x = (s0 > 0.f) ? 1.0f / sqrtf(fmaxf(s0, 1e-12f)) : 0.f;
    d.y = (s1 > 0.f) ? 1.0f / sqrtf(fmaxf(s1, 1e-12f)) : 0.f;
    d.z = (s2 > 0.f) ? 1.0f / sqrtf(fmaxf(s2, 1e-12f)) : 0.f;
    d.w = (s3 > 0.f) ? 1.0f / sqrtf(fmaxf(s3, 1e-12f)) : 0.f;
    d4n[n] = d;
}

extern "C" void kernel_launch(void* const* d_in, const int* in_sizes, int n_in,
                              void* d_out, int out_size, void* d_ws, size_t ws_size,
                              hipStream_t stream) {
    const float* eu = (const float*)d_in[0];
    const float* ei = (const float*)d_in[1];
    const int* head = (const int*)d_in[2];
    const int* tail = (const int*)d_in[3];
    float* out = (float*)d_out;   // 3-term accumulator, scaled at it3 (FL_FIN)

    // workspace layout — ~108 MB (16B-aligned first)
    float* A4 = (float*)d_ws;                               // 16 MB
    float* d4a = A4 + (size_t)NNZ_ * 4;                     // 1.6 MB
    float* d4b = d4a + (size_t)NN * 4;                      // 1.6 MB
    unsigned short* svals = (unsigned short*)(d4b + (size_t)NN * 4);  // 8 MB
    unsigned short* ego_a = svals + (size_t)NNZ_ * 4;       // 12.8 MB
    unsigned short* te_a  = ego_a + (size_t)NN * DIM_;      // 12.8 MB
    unsigned short* ego_b = te_a + (size_t)NN * DIM_;       // 12.8 MB
    unsigned short* te_b  = ego_b + (size_t)NN * DIM_;      // 12.8 MB
    unsigned short* fnb   = te_b + (size_t)NN * DIM_;       // 12.8 MB
    int2* bin = (int2*)(fnb + (size_t)NN * DIM_);           // 8 MB
    int* csr_tail = (int*)(bin + NNZ_);                     // 4 MB
    int* csr_head = csr_tail + NNZ_;                        // 4 MB
    int* row_start = csr_head + NNZ_;                       // NN+1
    int* bcount = row_start + (NN + 1);                     // NBLK
    int* bucket_base = bcount + NBLK;                       // NBLK+1
    int* bucket_cursor = bucket_base + (NBLK + 1);          // NBLK

    const int node_blocks = ceil_div(NN * DIM_, 256);      // 25000
    const int edge_blocks = ceil_div(NNZ_, 256);           // 3907
    const int wave_blocks = ceil_div(NN * 64, 256);        // 25000
    const int dinv_blocks = ceil_div(NN, 256);             // 391

    k_init<<<node_blocks, 256, 0, stream>>>(eu, ei, ego_a, te_a, out);

    // bucketed CSR build + d4_0 seed
    hipMemsetAsync(bcount, 0, NBLK * sizeof(int), stream);
    k_bcount<<<NBLK, 256, 0, stream>>>(head, bcount);
    k_bscan<<<1, 512, 0, stream>>>(bcount, bucket_base, bucket_cursor, &row_start[NN]);
    k_binscat<<<NBLK, 256, 0, stream>>>(head, tail, bucket_cursor, bin);
    k_bucket<<<NBLK, 256, 0, stream>>>(bin, bucket_base, row_start, (float4*)d4a, csr_tail);
    k_headfill<<<dinv_blocks, 256, 0, stream>>>(row_start, csr_head);

    // it0 = (0,0): walk1 with svals==0.25; fn -> fnb; scores A_old==1, store A_1.
    k_iter<FL_SVC | FL_FN><<<wave_blocks, 256, 0, stream>>>(
        svals, d4a, ego_a, row_start, csr_tail, out, fnb, ego_b, te_b);
    k_scores_edge<FL_ACONST | FL_ASTORE><<<edge_blocks, 256, 0, stream>>>(
        (float4*)A4, fnb, te_a, csr_head, csr_tail, (ushort4*)svals);
    k_dinv2<<<dinv_blocks, 256, 0, stream>>>((const ushort4*)svals, row_start, (float4*)d4b);

    // it1 = (0,1): layer-0 output; fn doubles as next ego (scores reads ego_b).
    k_iter<FL_OUT | FL_NEXT><<<wave_blocks, 256, 0, stream>>>(
        svals, d4b, ego_a, row_start, csr_tail, out, fnb, ego_b, te_b);
    k_scores_edge<FL_ASTORE><<<edge_blocks, 256, 0, stream>>>(
        (float4*)A4, ego_b, te_a, csr_head, csr_tail, (ushort4*)svals);
    k_dinv2<<<dinv_blocks, 256, 0, stream>>>((const ushort4*)svals, row_start, (float4*)d4a);

    // it2 = (1,0): fn -> fnb; scores store of A_3 dead (never read again).
    k_iter<FL_FN><<<wave_blocks, 256, 0, stream>>>(
        svals, d4a, ego_b, row_start, csr_tail, out, fnb, ego_a, te_a);
    k_scores_edge<0><<<edge_blocks, 256, 0, stream>>>(
        (float4*)A4, fnb, te_b, csr_head, csr_tail, (ushort4*)svals);
    k_dinv2<<<dinv_blocks, 256, 0, stream>>>((const ushort4*)svals, row_start, (float4*)d4b);

    // it3 = (1,1): no scores (dead); final out = (out + fn) / 3.
    k_iter<FL_OUT | FL_FIN><<<wave_blocks, 256, 0, stream>>>(
        svals, d4b, ego_b, row_start, csr_tail, out, fnb, ego_a, te_a);
}